// Round 4
// baseline (180.734 us; speedup 1.0000x reference)
//
#include <hip/hip_runtime.h>
#include <math.h>

// Problem dims (fixed)
#define BB 4
#define TT 1024
#define CC 1024
#define HH 16
#define DD 64
#define NQKV (3 * CC)      // 3072
#define MROWS (BB * TT)    // 4096

typedef __attribute__((ext_vector_type(8))) short bf16x8;   // 8 bf16 (4 VGPRs)
typedef __attribute__((ext_vector_type(4))) float f32x4;    // MFMA C/D

struct alignas(8) US4 { unsigned short x, y, z, w; };

__device__ __forceinline__ int imin(int a, int b) { return a < b ? a : b; }

__device__ __forceinline__ float b2f(unsigned short u) {
  unsigned int w = ((unsigned int)u) << 16;
  float f; __builtin_memcpy(&f, &w, 4); return f;
}
__device__ __forceinline__ unsigned short f2b(float f) {
  unsigned int u; __builtin_memcpy(&u, &f, 4);
  u += 0x7FFFu + ((u >> 16) & 1);        // RNE
  return (unsigned short)(u >> 16);
}

// raw hardware transcendentals: v_log_f32 (log2), v_exp_f32 (2^x)
__device__ __forceinline__ float hw_log2(float x) {
  return __builtin_amdgcn_logf(x);
}
__device__ __forceinline__ float hw_exp2(float x) {
  return __builtin_amdgcn_exp2f(x);
}

// async global->LDS, 16 B per lane; lds dest is wave-uniform base + lane*16
__device__ __forceinline__ void gload16(const void* g, void* l) {
  __builtin_amdgcn_global_load_lds(
      (const __attribute__((address_space(1))) unsigned int*)g,
      (__attribute__((address_space(3))) unsigned int*)l, 16, 0, 0);
}

// swizzled frag read: row_base points at a 128-B LDS row; logical 16-B chunk
// lc is stored at physical chunk lc ^ (row & 7).
__device__ __forceinline__ bf16x8 ld_sw(const unsigned short* row_base,
                                        int lc, int rsw) {
  return *(const bf16x8*)((const char*)row_base + (((lc ^ rsw) & 7) << 4));
}

// ---------------------------------------------------------------------------
// PREP (r19): one launch = W_qkv transpose | W_out transpose |
// spike flags + x->bf16 + zero ybufb rows for spike==0 (flash skips them).
// ---------------------------------------------------------------------------
__global__ __launch_bounds__(256) void prep(
    const float* __restrict__ x, const float* __restrict__ w_sur,
    const float* __restrict__ b_sur, const float* __restrict__ thr,
    const float* __restrict__ W_qkv, const float* __restrict__ W_out,
    float* __restrict__ spikes, unsigned short* __restrict__ xb,
    unsigned short* __restrict__ WqkvT, unsigned short* __restrict__ WoutT,
    unsigned short* __restrict__ ybufb) {
  __shared__ float t[32][33];
  const int blk = blockIdx.x;

  if (blk < 4096) {
    const float* W; unsigned short* WT; int K, N, bx, by;
    if (blk < 3072) {
      W = W_qkv; WT = WqkvT; K = CC; N = NQKV;
      bx = blk % 96; by = blk / 96;
    } else {
      W = W_out; WT = WoutT; K = CC; N = CC;
      const int b2 = blk - 3072;
      bx = b2 & 31; by = b2 >> 5;
    }
    const int tx = threadIdx.x & 31, ty = threadIdx.x >> 5;
    const int k0 = by * 32, n0 = bx * 32;
#pragma unroll
    for (int i = 0; i < 32; i += 8)
      t[ty + i][tx] = W[(size_t)(k0 + ty + i) * N + n0 + tx];
    __syncthreads();
#pragma unroll
    for (int i = 0; i < 32; i += 8)
      WT[(size_t)(n0 + ty + i) * K + k0 + tx] = f2b(t[tx][ty + i]);
  } else {
    const int row = (blk - 4096) * 4 + (threadIdx.x >> 6);
    const int lane = threadIdx.x & 63;
    const float* xr = x + (size_t)row * CC;
    unsigned short* xo = xb + (size_t)row * CC;
    double acc = 0.0;
#pragma unroll
    for (int s = 0; s < 4; ++s) {
      const int idx = s * 256 + lane * 4;
      const float4 xv = *(const float4*)(xr + idx);
      const float4 wv = *(const float4*)(w_sur + idx);
      acc += (double)xv.x * (double)wv.x;
      acc += (double)xv.y * (double)wv.y;
      acc += (double)xv.z * (double)wv.z;
      acc += (double)xv.w * (double)wv.w;
      US4 o = {f2b(xv.x), f2b(xv.y), f2b(xv.z), f2b(xv.w)};
      *(US4*)(xo + idx) = o;
    }
#pragma unroll
    for (int off = 32; off > 0; off >>= 1) acc += __shfl_xor(acc, off, 64);
    float spk = 0.f;
    if (lane == 0) {
      const float z = (float)acc + b_sur[0];
      const float imp = 1.0f / (1.0f + __expf(-z));
      spk = (imp > thr[0]) ? 1.0f : 0.0f;
      spikes[row] = spk;
    }
    spk = __shfl(spk, 0, 64);
    if (spk == 0.f) {
      // attention output for this query row is exactly zero
      unsigned short* yz = ybufb + (size_t)row * CC;
      const bf16x8 z8 = {};
      *(bf16x8*)&yz[lane * 16] = z8;
      *(bf16x8*)&yz[lane * 16 + 8] = z8;
    }
  }
}

// ---------------------------------------------------------------------------
// COMPACT (new, r19): per batch, order-preserving index list of spike rows.
// 4 blocks x 1024 threads; ballot + wave prefix + serial 16-wave scan.
// ---------------------------------------------------------------------------
__global__ __launch_bounds__(1024) void compact(
    const float* __restrict__ spikes, unsigned short* __restrict__ cidx,
    int* __restrict__ cnt) {
  const int b = blockIdx.x;
  const int t = threadIdx.x;
  const int lane = t & 63, wv = t >> 6;       // 16 waves
  __shared__ int wsum[16];
  __shared__ int woff[16];
  const bool f = spikes[b * TT + t] > 0.5f;
  const unsigned long long bal = __ballot(f);
  const int wpre = __popcll(bal & ((1ull << lane) - 1ull));
  if (lane == 0) wsum[wv] = __popcll(bal);
  __syncthreads();
  if (t == 0) {
    int s = 0;
#pragma unroll
    for (int i = 0; i < 16; ++i) { woff[i] = s; s += wsum[i]; }
    cnt[b] = s;
  }
  __syncthreads();
  if (f) cidx[b * TT + woff[wv] + wpre] = (unsigned short)t;
}

// ---------------------------------------------------------------------------
// QKV GEMM + fused Lorentz + fused V-transpose (r18, kept).
// ---------------------------------------------------------------------------
__global__ __launch_bounds__(256, 3) void gemm_qkv(
    const unsigned short* __restrict__ A, const unsigned short* __restrict__ BT,
    const float* __restrict__ bias, unsigned short* __restrict__ qkvb,
    unsigned short* __restrict__ vT) {
  const int K = CC;
  __shared__ unsigned short SH[16384];     // 32 KB: As 128x64 | Bs 128x64
  unsigned short (*As)[64] = (unsigned short(*)[64])SH;
  unsigned short (*Bs)[64] = (unsigned short(*)[64])(SH + 8192);
  const int tid = threadIdx.x;
  const int lane = tid & 63;
  const int wave = tid >> 6;
  const int wr = wave >> 1;            // wave row 0..1 (64 rows each)
  const int wc = wave & 1;             // wave col 0..1 (64 cols each)
  const int m0 = blockIdx.y * 128;
  const int n0 = blockIdx.x * 128;
  const int ln15 = lane & 15;
  const int g = lane >> 4;
  const int rsw = ln15 & 7;            // frag-read swizzle key

  const int srow = tid >> 3;           // 0..31
  const int schk = ((tid & 7) ^ (srow & 7)) * 8;   // swizzled fetch chunk
  const unsigned short* gA = A + (size_t)(m0 + srow) * K + schk;
  const unsigned short* gB = BT + (size_t)(n0 + srow) * K + schk;
  char* lA = (char*)SH + wave * 1024;
  char* lB = (char*)SH + 16384 + wave * 1024;

  f32x4 acc[4][4] = {};

  for (int k0 = 0; k0 < K; k0 += 64) {
    __syncthreads();
#pragma unroll
    for (int i = 0; i < 4; ++i)
      gload16(gA + k0 + (size_t)(32 * i) * K, lA + i * 4096);
#pragma unroll
    for (int i = 0; i < 4; ++i)
      gload16(gB + k0 + (size_t)(32 * i) * K, lB + i * 4096);
    __syncthreads();

#pragma unroll
    for (int c = 0; c < 2; ++c) {
      bf16x8 af[4], bfr[4];
#pragma unroll
      for (int i = 0; i < 4; ++i)
        af[i] = ld_sw(&As[wr * 64 + i * 16 + ln15][0], c * 4 + g, rsw);
#pragma unroll
      for (int j = 0; j < 4; ++j)
        bfr[j] = ld_sw(&Bs[wc * 64 + j * 16 + ln15][0], c * 4 + g, rsw);
#pragma unroll
      for (int i = 0; i < 4; ++i)
#pragma unroll
        for (int j = 0; j < 4; ++j)
          acc[i][j] = __builtin_amdgcn_mfma_f32_16x16x32_bf16(
              af[i], bfr[j], acc[i][j], 0, 0, 0);
    }
  }

  __syncthreads();                       // all MFMA frag reads done
  unsigned short* scr = SH + wave * 4096;  // per-wave 64x64 scratch (8 KB)

  const int bx = blockIdx.x;             // segment id: q<8, k<16, v else
  if (bx < 16) {
    const bool isk = (bx >= 8);
#pragma unroll
    for (int i = 0; i < 4; ++i) {
#pragma unroll
      for (int r = 0; r < 4; ++r) {
        float u[4];
        float part = 0.f;
#pragma unroll
        for (int j = 0; j < 4; ++j) {
          u[j] = acc[i][j][r] + bias[n0 + wc * 64 + j * 16 + ln15];
          float sq = u[j] * u[j];
          if (j == 0 && ln15 == 0) sq = -sq;     // time component
          part += sq;
        }
#pragma unroll
        for (int off = 1; off < 16; off <<= 1)
          part += __shfl_xor(part, off, 64);
        const float nomin = sqrtf(fmaxf(part, 1e-8f));
        const float e = __expf(nomin);
        const float ei = __builtin_amdgcn_rcpf(e);
        const float tim = 0.5f * (e + ei);
        const float coef = 0.5f * (e - ei) * __builtin_amdgcn_rcpf(nomin);
        const int lrow = i * 16 + g * 4 + r;     // token-local 0..63
#pragma unroll
        for (int j = 0; j < 4; ++j) {
          float o = (j == 0 && ln15 == 0) ? tim : coef * u[j];
          if (isk && !(j == 0 && ln15 == 0)) o = -o;
          const int col = j * 16 + ln15;
          const int ch = ((col >> 3) + lrow) & 7;
          scr[lrow * 64 + ch * 8 + (col & 7)] = f2b(o);
        }
      }
    }
#pragma unroll
    for (int it = 0; it < 8; ++it) {
      const int row = (lane >> 3) + 8 * it;    // 0..63
      const int ch = lane & 7;
      const int ph = (ch + row) & 7;
      const bf16x8 v = *(const bf16x8*)&scr[row * 64 + ph * 8];
      *(bf16x8*)&qkvb[(size_t)(m0 + wr * 64 + row) * NQKV + n0 + wc * 64 + ch * 8] = v;
    }
  } else {
#pragma unroll
    for (int i = 0; i < 4; ++i) {
#pragma unroll
      for (int j = 0; j < 4; ++j) {
        const float bb_ = bias[n0 + wc * 64 + j * 16 + ln15];
        const int drow = j * 16 + ln15;          // 0..63
#pragma unroll
        for (int r = 0; r < 4; ++r) {
          const int col = i * 16 + g * 4 + r;    // t-local 0..63
          const int ch = ((col >> 3) + drow) & 7;
          scr[drow * 64 + ch * 8 + (col & 7)] = f2b(acc[i][j][r] + bb_);
        }
      }
    }
    const int hh = (bx - 16) * 2 + wc;
    const int mbase = m0 + wr * 64;
    const int bq = mbase >> 10;
    const int t0 = mbase & 1023;
#pragma unroll
    for (int it = 0; it < 8; ++it) {
      const int drow = (lane >> 3) + 8 * it;   // 0..63
      const int ch = lane & 7;
      const int ph = (ch + drow) & 7;
      const bf16x8 v = *(const bf16x8*)&scr[drow * 64 + ph * 8];
      *(bf16x8*)&vT[((size_t)(bq * HH + hh) * DD + drow) * TT + t0 + ch * 8] = v;
    }
  }
}

// ---------------------------------------------------------------------------
// Out GEMM (verified r15): 128x64 tiles, 2/CU, XOR chunk swizzle.
// ---------------------------------------------------------------------------
__global__ __launch_bounds__(256) void gemm_out(
    const unsigned short* __restrict__ A, const unsigned short* __restrict__ BT,
    const float* __restrict__ bias, float* __restrict__ C) {
  const int N = CC, K = CC;
  __shared__ unsigned short As[128][64];   // 16 KB
  __shared__ unsigned short Bs[64][64];    // 8 KB
  const int tid = threadIdx.x;
  const int lane = tid & 63;
  const int wave = tid >> 6;
  const int wm = wave * 32;
  const int m0 = blockIdx.y * 128;
  const int n0 = blockIdx.x * 64;
  const int ln15 = lane & 15;
  const int g = lane >> 4;
  const int rsw = ln15 & 7;

  const int srow = tid >> 3;           // 0..31
  const int schk = ((tid & 7) ^ (srow & 7)) * 8;
  const unsigned short* gA = A + (size_t)(m0 + srow) * K + schk;
  const unsigned short* gB = BT + (size_t)(n0 + srow) * K + schk;
  char* lA = (char*)As + wave * 1024;
  char* lB = (char*)Bs + wave * 1024;

  f32x4 acc[2][4] = {};

  for (int k0 = 0; k0 < K; k0 += 64) {
    __syncthreads();
#pragma unroll
    for (int i = 0; i < 4; ++i)
      gload16(gA + k0 + (size_t)(32 * i) * K, lA + i * 4096);
#pragma unroll
    for (int i = 0; i < 2; ++i)
      gload16(gB + k0 + (size_t)(32 * i) * K, lB + i * 4096);
    __syncthreads();

#pragma unroll
    for (int c = 0; c < 2; ++c) {
      bf16x8 af[2], bfr[4];
#pragma unroll
      for (int i = 0; i < 2; ++i)
        af[i] = ld_sw(&As[wm + i * 16 + ln15][0], c * 4 + g, rsw);
#pragma unroll
      for (int j = 0; j < 4; ++j)
        bfr[j] = ld_sw(&Bs[j * 16 + ln15][0], c * 4 + g, rsw);
#pragma unroll
      for (int i = 0; i < 2; ++i)
#pragma unroll
        for (int j = 0; j < 4; ++j)
          acc[i][j] = __builtin_amdgcn_mfma_f32_16x16x32_bf16(
              af[i], bfr[j], acc[i][j], 0, 0, 0);
    }
  }

#pragma unroll
  for (int i = 0; i < 2; ++i) {
#pragma unroll
    for (int r = 0; r < 4; ++r) {
      const int m = m0 + wm + i * 16 + g * 4 + r;
#pragma unroll
      for (int j = 0; j < 4; ++j) {
        const int n = n0 + j * 16 + ln15;
        C[(size_t)m * N + n] = acc[i][j][r] + bias[n];
      }
    }
  }
}

// ---------------------------------------------------------------------------
// MFMA flash over COMPACTED query rows (r19). ~50% of query rows have
// spike==0 and produce exactly-zero output (pre-zeroed in prep); this kernel
// only processes the surviving rows, gathered via cidx (order-preserving, so
// the causal mask uses original indices oi). K/V staging is unchanged
// (keys are never masked by spikes). Partial tail bands clamp to the last
// valid row (duplicate compute, stores guarded by slot<cnt).
// LDS: Ks[128][68] + Vs[64][136] + Ps[128][68] = 52.2 KB.
// ---------------------------------------------------------------------------
__global__ __launch_bounds__(512) void flash_mfma(
    const unsigned short* __restrict__ qkv, const unsigned short* __restrict__ vT,
    const unsigned short* __restrict__ cidx, const int* __restrict__ cntp,
    unsigned short* __restrict__ y) {
  __shared__ unsigned short Ks[128][68];
  __shared__ unsigned short Vs[64][136];   // Vs[d][t-local 0..127]
  __shared__ unsigned short Ps[128][68];

  const int tid = threadIdx.x;
  const int lane = tid & 63;
  const int wave = tid >> 6;              // 0..7
  const int ln15 = lane & 15;
  const int g = lane >> 4;
  const int bh = blockIdx.y;
  const int itile = (bh < 32) ? ((int)gridDim.x - 1 - (int)blockIdx.x)
                              : (int)blockIdx.x;   // balanced pairing
  const int b = bh >> 4;
  const int h = bh & 15;
  const int i0 = itile * 128;             // compacted-row tile base
  const int band = wave * 16;

  const int cnt = cntp[b];
  if (i0 >= cnt) return;                  // block-uniform early exit

  // original index of the block's last row -> K/V iteration count
  const int omax_blk = cidx[b * TT + imin(i0 + 127, cnt - 1)];
  const int htiles = omax_blk / 128 + 1;  // 128-col iterations

  const unsigned short* base = qkv + (size_t)b * TT * NQKV;
  const unsigned short* vbase = vT + (size_t)bh * DD * TT;  // rows d, cols t
  const int qoff = h * DD;
  const int koff = CC + h * DD;

  // staging coords
  const int ksn = tid >> 2;            // K row 0..127
  const int kqc = (tid & 3) * 2;       // two 16-B chunks of the 128-B row
  const int vsn = tid >> 3;            // V d-row 0..63
  const int vqc = (tid & 7) * 2;       // two 16-B chunks of the 256-B row

  // per-lane compacted slot -> original query row (clamped duplicates at tail)
  const int qslot = imin(i0 + band + ln15, cnt - 1);
  const int qorig = (int)cidx[b * TT + qslot];
  int oi_[4];
#pragma unroll
  for (int r = 0; r < 4; ++r) oi_[r] = __shfl(qorig, g * 4 + r, 16);
  const int obandmin = __shfl(qorig, 0, 16);
  const int obandmax = __shfl(qorig, 15, 16);

  bf16x8 qf[2];
  {
    const unsigned short* qp = base + (size_t)qorig * NQKV + qoff;
    qf[0] = *(const bf16x8*)(qp + g * 8);
    qf[1] = *(const bf16x8*)(qp + 32 + g * 8);
  }

  f32x4 accy[4] = {};           // y[m=g*4+r][d=dt*16+ln15] (unnormalized)
  float lrow[4] = {0.f, 0.f, 0.f, 0.f};

  // prefetch iteration 0
  float4 kr0, kr1, vr0, vr1;
  {
    const unsigned short* kp = base + (size_t)ksn * NQKV + koff + kqc * 8;
    const unsigned short* vp = vbase + (size_t)vsn * TT + vqc * 8;
    kr0 = *(const float4*)(kp + 0);
    kr1 = *(const float4*)(kp + 8);
    vr0 = *(const float4*)(vp + 0);
    vr1 = *(const float4*)(vp + 8);
  }

  for (int ht = 0; ht < htiles; ++ht) {
    const int j0h = ht * 128;
    __syncthreads();                       // prior-iter Ks/Vs consumers done
    *(float4*)&Ks[ksn][kqc * 8 + 0] = kr0;
    *(float4*)&Ks[ksn][kqc * 8 + 8] = kr1;
    *(float4*)&Vs[vsn][vqc * 8 + 0] = vr0;
    *(float4*)&Vs[vsn][vqc * 8 + 8] = vr1;
    __syncthreads();

    // prefetch next iteration (overlaps with compute below)
    if (ht + 1 < htiles) {
      const int j1 = j0h + 128;
      const unsigned short* kp = base + (size_t)(j1 + ksn) * NQKV + koff + kqc * 8;
      const unsigned short* vp = vbase + (size_t)vsn * TT + j1 + vqc * 8;
      kr0 = *(const float4*)(kp + 0);
      kr1 = *(const float4*)(kp + 8);
      vr0 = *(const float4*)(vp + 0);
      vr1 = *(const float4*)(vp + 8);
    }

#pragma unroll
    for (int t2 = 0; t2 < 2; ++t2) {
      const int j0 = j0h + t2 * 64;
      if (j0 > obandmax) continue;         // fully masked for this band

      // S = Q . K^T  (K rows t2*64 .. +63)
      f32x4 sf[4];
#pragma unroll
      for (int j = 0; j < 4; ++j) {
        const bf16x8 k0 = *(const bf16x8*)&Ks[t2 * 64 + j * 16 + ln15][g * 8];
        const bf16x8 k1 = *(const bf16x8*)&Ks[t2 * 64 + j * 16 + ln15][32 + g * 8];
        f32x4 z = {};
        z = __builtin_amdgcn_mfma_f32_16x16x32_bf16(qf[0], k0, z, 0, 0, 0);
        sf[j] = __builtin_amdgcn_mfma_f32_16x16x32_bf16(qf[1], k1, z, 0, 0, 0);
      }

      // p = exp2(-(ln2/8) * (log2(z)+1)^2);  ln2/8 = 0.08664339757
      float p[4][4];
      if (j0 + 63 <= obandmin) {
        // unmasked fast path (strictly at/below diagonal for all band rows)
#pragma unroll
        for (int j = 0; j < 4; ++j)
#pragma unroll
          for (int r = 0; r < 4; ++r) {
            const float l = hw_log2(fmaxf(sf[j][r], 1.0f));
            const float s = l + 1.0f;
            p[r][j] = hw_exp2(-0.08664339757f * s * s);
          }
      } else {
#pragma unroll
        for (int j = 0; j < 4; ++j) {
          const int gj = j0 + j * 16 + ln15;
#pragma unroll
          for (int r = 0; r < 4; ++r) {
            float e;
            if (gj > oi_[r]) {
              e = 0.f;
            } else {
              const float l = hw_log2(fmaxf(sf[j][r], 1.0f));
              const float s = l + 1.0f;
              e = hw_exp2(-0.08664339757f * s * s);
            }
            p[r][j] = e;
          }
        }
      }
#pragma unroll
      for (int r = 0; r < 4; ++r)
        lrow[r] += (p[r][0] + p[r][1]) + (p[r][2] + p[r][3]);

      // P -> LDS (bf16, A-layout); intra-wave producer/consumer, no barrier
#pragma unroll
      for (int r = 0; r < 4; ++r)
#pragma unroll
        for (int j = 0; j < 4; ++j)
          Ps[band + g * 4 + r][j * 16 + ln15] = f2b(p[r][j]);

      const bf16x8 pa0 = *(const bf16x8*)&Ps[band + ln15][g * 8];
      const bf16x8 pa1 = *(const bf16x8*)&Ps[band + ln15][32 + g * 8];
#pragma unroll
      for (int dt = 0; dt < 4; ++dt) {
        const bf16x8 v0 = *(const bf16x8*)&Vs[dt * 16 + ln15][t2 * 64 + g * 8];
        const bf16x8 v1 = *(const bf16x8*)&Vs[dt * 16 + ln15][t2 * 64 + 32 + g * 8];
        accy[dt] = __builtin_amdgcn_mfma_f32_16x16x32_bf16(pa0, v0, accy[dt], 0, 0, 0);
        accy[dt] = __builtin_amdgcn_mfma_f32_16x16x32_bf16(pa1, v1, accy[dt], 0, 0, 0);
      }
    }
  }

  // epilogue: reduce lrow across the 16 n-lanes, scale, scatter-store
#pragma unroll
  for (int r = 0; r < 4; ++r) {
#pragma unroll
    for (int off = 1; off < 16; off <<= 1)
      lrow[r] += __shfl_xor(lrow[r], off, 64);
  }
#pragma unroll
  for (int r = 0; r < 4; ++r) {
    const int slot = i0 + band + g * 4 + r;
    if (slot < cnt) {                      // guard tail duplicates
      const float scale = 1.0f / lrow[r];  // surviving rows: spike == 1
      const size_t yrow = (size_t)(b * TT + oi_[r]);
#pragma unroll
      for (int dt = 0; dt < 4; ++dt)
        y[yrow * CC + h * DD + dt * 16 + ln15] = f2b(accy[dt][r] * scale);
    }
  }
}

// ---------------------------------------------------------------------------
extern "C" void kernel_launch(void* const* d_in, const int* in_sizes, int n_in,
                              void* d_out, int out_size, void* d_ws, size_t ws_size,
                              hipStream_t stream) {
  const float* x     = (const float*)d_in[0];
  const float* W_qkv = (const float*)d_in[1];
  const float* b_qkv = (const float*)d_in[2];
  const float* W_out = (const float*)d_in[3];
  const float* b_out = (const float*)d_in[4];
  const float* w_sur = (const float*)d_in[5];
  const float* b_sur = (const float*)d_in[6];
  const float* thr   = (const float*)d_in[7];
  float* out = (float*)d_out;

  // ws layout (bytes):
  //   xb 8.39M | qkvb 25.17M | vT 8.39M | ybufb 8.39M | WqkvT 6.29M |
  //   WoutT 2.10M | spikes 16K | cidx 8K | count 16B
  char* w = (char*)d_ws;
  unsigned short* xb    = (unsigned short*)(w);
  unsigned short* qkvb  = (unsigned short*)(w + 8388608);
  unsigned short* vTb   = (unsigned short*)(w + 8388608 + 25165824);
  unsigned short* ybufb = (unsigned short*)(w + 8388608 + 25165824 + 8388608);
  unsigned short* WqkvT = (unsigned short*)(w + 8388608 + 25165824 + 2 * 8388608);
  unsigned short* WoutT = (unsigned short*)(w + 8388608 + 25165824 + 2 * 8388608 + 6291456);
  float* spikes = (float*)(w + 58720256);
  unsigned short* cidx = (unsigned short*)(w + 58720256 + 16384);
  int* cnt = (int*)(w + 58720256 + 16384 + 8192);

  prep<<<5120, 256, 0, stream>>>(x, w_sur, b_sur, thr, W_qkv, W_out,
                                 spikes, xb, WqkvT, WoutT, ybufb);

  compact<<<4, 1024, 0, stream>>>(spikes, cidx, cnt);

  gemm_qkv<<<dim3(NQKV / 128, MROWS / 128), 256, 0, stream>>>(
      xb, WqkvT, b_qkv, qkvb, vTb);

  flash_mfma<<<dim3(TT / 128, BB * HH), 512, 0, stream>>>(qkvb, vTb, cidx, cnt, ybufb);

  gemm_out<<<dim3(CC / 64, MROWS / 128), 256, 0, stream>>>(
      ybufb, WoutT, b_out, out);
}

// Round 5
// 174.389 us; speedup vs baseline: 1.0364x; 1.0364x over previous
//
#include <hip/hip_runtime.h>
#include <math.h>

// Problem dims (fixed)
#define BB 4
#define TT 1024
#define CC 1024
#define HH 16
#define DD 64
#define NQKV (3 * CC)      // 3072
#define MROWS (BB * TT)    // 4096

typedef __attribute__((ext_vector_type(8))) short bf16x8;   // 8 bf16 (4 VGPRs)
typedef __attribute__((ext_vector_type(4))) float f32x4;    // MFMA C/D

struct alignas(8) US4 { unsigned short x, y, z, w; };

__device__ __forceinline__ int imin(int a, int b) { return a < b ? a : b; }

__device__ __forceinline__ float b2f(unsigned short u) {
  unsigned int w = ((unsigned int)u) << 16;
  float f; __builtin_memcpy(&f, &w, 4); return f;
}
__device__ __forceinline__ unsigned short f2b(float f) {
  unsigned int u; __builtin_memcpy(&u, &f, 4);
  u += 0x7FFFu + ((u >> 16) & 1);        // RNE
  return (unsigned short)(u >> 16);
}

// raw hardware transcendentals: v_log_f32 (log2), v_exp_f32 (2^x)
__device__ __forceinline__ float hw_log2(float x) {
  return __builtin_amdgcn_logf(x);
}
__device__ __forceinline__ float hw_exp2(float x) {
  return __builtin_amdgcn_exp2f(x);
}

// async global->LDS, 16 B per lane; lds dest is wave-uniform base + lane*16
__device__ __forceinline__ void gload16(const void* g, void* l) {
  __builtin_amdgcn_global_load_lds(
      (const __attribute__((address_space(1))) unsigned int*)g,
      (__attribute__((address_space(3))) unsigned int*)l, 16, 0, 0);
}

// swizzled frag read: row_base points at a 128-B LDS row; logical 16-B chunk
// lc is stored at physical chunk lc ^ (row & 7).
__device__ __forceinline__ bf16x8 ld_sw(const unsigned short* row_base,
                                        int lc, int rsw) {
  return *(const bf16x8*)((const char*)row_base + (((lc ^ rsw) & 7) << 4));
}

// ---------------------------------------------------------------------------
// PREP (r19): one launch = W_qkv transpose | W_out transpose |
// spike flags + x->bf16 + zero ybufb rows for spike==0 (flash skips them).
// ---------------------------------------------------------------------------
__global__ __launch_bounds__(256) void prep(
    const float* __restrict__ x, const float* __restrict__ w_sur,
    const float* __restrict__ b_sur, const float* __restrict__ thr,
    const float* __restrict__ W_qkv, const float* __restrict__ W_out,
    float* __restrict__ spikes, unsigned short* __restrict__ xb,
    unsigned short* __restrict__ WqkvT, unsigned short* __restrict__ WoutT,
    unsigned short* __restrict__ ybufb) {
  __shared__ float t[32][33];
  const int blk = blockIdx.x;

  if (blk < 4096) {
    const float* W; unsigned short* WT; int K, N, bx, by;
    if (blk < 3072) {
      W = W_qkv; WT = WqkvT; K = CC; N = NQKV;
      bx = blk % 96; by = blk / 96;
    } else {
      W = W_out; WT = WoutT; K = CC; N = CC;
      const int b2 = blk - 3072;
      bx = b2 & 31; by = b2 >> 5;
    }
    const int tx = threadIdx.x & 31, ty = threadIdx.x >> 5;
    const int k0 = by * 32, n0 = bx * 32;
#pragma unroll
    for (int i = 0; i < 32; i += 8)
      t[ty + i][tx] = W[(size_t)(k0 + ty + i) * N + n0 + tx];
    __syncthreads();
#pragma unroll
    for (int i = 0; i < 32; i += 8)
      WT[(size_t)(n0 + ty + i) * K + k0 + tx] = f2b(t[tx][ty + i]);
  } else {
    const int row = (blk - 4096) * 4 + (threadIdx.x >> 6);
    const int lane = threadIdx.x & 63;
    const float* xr = x + (size_t)row * CC;
    unsigned short* xo = xb + (size_t)row * CC;
    double acc = 0.0;
#pragma unroll
    for (int s = 0; s < 4; ++s) {
      const int idx = s * 256 + lane * 4;
      const float4 xv = *(const float4*)(xr + idx);
      const float4 wv = *(const float4*)(w_sur + idx);
      acc += (double)xv.x * (double)wv.x;
      acc += (double)xv.y * (double)wv.y;
      acc += (double)xv.z * (double)wv.z;
      acc += (double)xv.w * (double)wv.w;
      US4 o = {f2b(xv.x), f2b(xv.y), f2b(xv.z), f2b(xv.w)};
      *(US4*)(xo + idx) = o;
    }
#pragma unroll
    for (int off = 32; off > 0; off >>= 1) acc += __shfl_xor(acc, off, 64);
    float spk = 0.f;
    if (lane == 0) {
      const float z = (float)acc + b_sur[0];
      const float imp = 1.0f / (1.0f + __expf(-z));
      spk = (imp > thr[0]) ? 1.0f : 0.0f;
      spikes[row] = spk;
    }
    spk = __shfl(spk, 0, 64);
    if (spk == 0.f) {
      // attention output for this query row is exactly zero
      unsigned short* yz = ybufb + (size_t)row * CC;
      const bf16x8 z8 = {};
      *(bf16x8*)&yz[lane * 16] = z8;
      *(bf16x8*)&yz[lane * 16 + 8] = z8;
    }
  }
}

// ---------------------------------------------------------------------------
// COMPACT (r19): per batch, order-preserving index list of spike rows.
// ---------------------------------------------------------------------------
__global__ __launch_bounds__(1024) void compact(
    const float* __restrict__ spikes, unsigned short* __restrict__ cidx,
    int* __restrict__ cnt) {
  const int b = blockIdx.x;
  const int t = threadIdx.x;
  const int lane = t & 63, wv = t >> 6;       // 16 waves
  __shared__ int wsum[16];
  __shared__ int woff[16];
  const bool f = spikes[b * TT + t] > 0.5f;
  const unsigned long long bal = __ballot(f);
  const int wpre = __popcll(bal & ((1ull << lane) - 1ull));
  if (lane == 0) wsum[wv] = __popcll(bal);
  __syncthreads();
  if (t == 0) {
    int s = 0;
#pragma unroll
    for (int i = 0; i < 16; ++i) { woff[i] = s; s += wsum[i]; }
    cnt[b] = s;
  }
  __syncthreads();
  if (f) cidx[b * TT + woff[wv] + wpre] = (unsigned short)t;
}

// ---------------------------------------------------------------------------
// QKV GEMM + fused Lorentz + fused V-transpose (r18, kept).
// ---------------------------------------------------------------------------
__global__ __launch_bounds__(256, 3) void gemm_qkv(
    const unsigned short* __restrict__ A, const unsigned short* __restrict__ BT,
    const float* __restrict__ bias, unsigned short* __restrict__ qkvb,
    unsigned short* __restrict__ vT) {
  const int K = CC;
  __shared__ unsigned short SH[16384];     // 32 KB: As 128x64 | Bs 128x64
  unsigned short (*As)[64] = (unsigned short(*)[64])SH;
  unsigned short (*Bs)[64] = (unsigned short(*)[64])(SH + 8192);
  const int tid = threadIdx.x;
  const int lane = tid & 63;
  const int wave = tid >> 6;
  const int wr = wave >> 1;            // wave row 0..1 (64 rows each)
  const int wc = wave & 1;             // wave col 0..1 (64 cols each)
  const int m0 = blockIdx.y * 128;
  const int n0 = blockIdx.x * 128;
  const int ln15 = lane & 15;
  const int g = lane >> 4;
  const int rsw = ln15 & 7;            // frag-read swizzle key

  const int srow = tid >> 3;           // 0..31
  const int schk = ((tid & 7) ^ (srow & 7)) * 8;   // swizzled fetch chunk
  const unsigned short* gA = A + (size_t)(m0 + srow) * K + schk;
  const unsigned short* gB = BT + (size_t)(n0 + srow) * K + schk;
  char* lA = (char*)SH + wave * 1024;
  char* lB = (char*)SH + 16384 + wave * 1024;

  f32x4 acc[4][4] = {};

  for (int k0 = 0; k0 < K; k0 += 64) {
    __syncthreads();
#pragma unroll
    for (int i = 0; i < 4; ++i)
      gload16(gA + k0 + (size_t)(32 * i) * K, lA + i * 4096);
#pragma unroll
    for (int i = 0; i < 4; ++i)
      gload16(gB + k0 + (size_t)(32 * i) * K, lB + i * 4096);
    __syncthreads();

#pragma unroll
    for (int c = 0; c < 2; ++c) {
      bf16x8 af[4], bfr[4];
#pragma unroll
      for (int i = 0; i < 4; ++i)
        af[i] = ld_sw(&As[wr * 64 + i * 16 + ln15][0], c * 4 + g, rsw);
#pragma unroll
      for (int j = 0; j < 4; ++j)
        bfr[j] = ld_sw(&Bs[wc * 64 + j * 16 + ln15][0], c * 4 + g, rsw);
#pragma unroll
      for (int i = 0; i < 4; ++i)
#pragma unroll
        for (int j = 0; j < 4; ++j)
          acc[i][j] = __builtin_amdgcn_mfma_f32_16x16x32_bf16(
              af[i], bfr[j], acc[i][j], 0, 0, 0);
    }
  }

  __syncthreads();                       // all MFMA frag reads done
  unsigned short* scr = SH + wave * 4096;  // per-wave 64x64 scratch (8 KB)

  const int bx = blockIdx.x;             // segment id: q<8, k<16, v else
  if (bx < 16) {
    const bool isk = (bx >= 8);
#pragma unroll
    for (int i = 0; i < 4; ++i) {
#pragma unroll
      for (int r = 0; r < 4; ++r) {
        float u[4];
        float part = 0.f;
#pragma unroll
        for (int j = 0; j < 4; ++j) {
          u[j] = acc[i][j][r] + bias[n0 + wc * 64 + j * 16 + ln15];
          float sq = u[j] * u[j];
          if (j == 0 && ln15 == 0) sq = -sq;     // time component
          part += sq;
        }
#pragma unroll
        for (int off = 1; off < 16; off <<= 1)
          part += __shfl_xor(part, off, 64);
        const float nomin = sqrtf(fmaxf(part, 1e-8f));
        const float e = __expf(nomin);
        const float ei = __builtin_amdgcn_rcpf(e);
        const float tim = 0.5f * (e + ei);
        const float coef = 0.5f * (e - ei) * __builtin_amdgcn_rcpf(nomin);
        const int lrow = i * 16 + g * 4 + r;     // token-local 0..63
#pragma unroll
        for (int j = 0; j < 4; ++j) {
          float o = (j == 0 && ln15 == 0) ? tim : coef * u[j];
          if (isk && !(j == 0 && ln15 == 0)) o = -o;
          const int col = j * 16 + ln15;
          const int ch = ((col >> 3) + lrow) & 7;
          scr[lrow * 64 + ch * 8 + (col & 7)] = f2b(o);
        }
      }
    }
#pragma unroll
    for (int it = 0; it < 8; ++it) {
      const int row = (lane >> 3) + 8 * it;    // 0..63
      const int ch = lane & 7;
      const int ph = (ch + row) & 7;
      const bf16x8 v = *(const bf16x8*)&scr[row * 64 + ph * 8];
      *(bf16x8*)&qkvb[(size_t)(m0 + wr * 64 + row) * NQKV + n0 + wc * 64 + ch * 8] = v;
    }
  } else {
#pragma unroll
    for (int i = 0; i < 4; ++i) {
#pragma unroll
      for (int j = 0; j < 4; ++j) {
        const float bb_ = bias[n0 + wc * 64 + j * 16 + ln15];
        const int drow = j * 16 + ln15;          // 0..63
#pragma unroll
        for (int r = 0; r < 4; ++r) {
          const int col = i * 16 + g * 4 + r;    // t-local 0..63
          const int ch = ((col >> 3) + drow) & 7;
          scr[drow * 64 + ch * 8 + (col & 7)] = f2b(acc[i][j][r] + bb_);
        }
      }
    }
    const int hh = (bx - 16) * 2 + wc;
    const int mbase = m0 + wr * 64;
    const int bq = mbase >> 10;
    const int t0 = mbase & 1023;
#pragma unroll
    for (int it = 0; it < 8; ++it) {
      const int drow = (lane >> 3) + 8 * it;   // 0..63
      const int ch = lane & 7;
      const int ph = (ch + drow) & 7;
      const bf16x8 v = *(const bf16x8*)&scr[drow * 64 + ph * 8];
      *(bf16x8*)&vT[((size_t)(bq * HH + hh) * DD + drow) * TT + t0 + ch * 8] = v;
    }
  }
}

// ---------------------------------------------------------------------------
// Out GEMM (verified r15): 128x64 tiles, 2/CU, XOR chunk swizzle.
// ---------------------------------------------------------------------------
__global__ __launch_bounds__(256) void gemm_out(
    const unsigned short* __restrict__ A, const unsigned short* __restrict__ BT,
    const float* __restrict__ bias, float* __restrict__ C) {
  const int N = CC, K = CC;
  __shared__ unsigned short As[128][64];   // 16 KB
  __shared__ unsigned short Bs[64][64];    // 8 KB
  const int tid = threadIdx.x;
  const int lane = tid & 63;
  const int wave = tid >> 6;
  const int wm = wave * 32;
  const int m0 = blockIdx.y * 128;
  const int n0 = blockIdx.x * 64;
  const int ln15 = lane & 15;
  const int g = lane >> 4;
  const int rsw = ln15 & 7;

  const int srow = tid >> 3;           // 0..31
  const int schk = ((tid & 7) ^ (srow & 7)) * 8;
  const unsigned short* gA = A + (size_t)(m0 + srow) * K + schk;
  const unsigned short* gB = BT + (size_t)(n0 + srow) * K + schk;
  char* lA = (char*)As + wave * 1024;
  char* lB = (char*)Bs + wave * 1024;

  f32x4 acc[2][4] = {};

  for (int k0 = 0; k0 < K; k0 += 64) {
    __syncthreads();
#pragma unroll
    for (int i = 0; i < 4; ++i)
      gload16(gA + k0 + (size_t)(32 * i) * K, lA + i * 4096);
#pragma unroll
    for (int i = 0; i < 2; ++i)
      gload16(gB + k0 + (size_t)(32 * i) * K, lB + i * 4096);
    __syncthreads();

#pragma unroll
    for (int c = 0; c < 2; ++c) {
      bf16x8 af[2], bfr[4];
#pragma unroll
      for (int i = 0; i < 2; ++i)
        af[i] = ld_sw(&As[wm + i * 16 + ln15][0], c * 4 + g, rsw);
#pragma unroll
      for (int j = 0; j < 4; ++j)
        bfr[j] = ld_sw(&Bs[j * 16 + ln15][0], c * 4 + g, rsw);
#pragma unroll
      for (int i = 0; i < 2; ++i)
#pragma unroll
        for (int j = 0; j < 4; ++j)
          acc[i][j] = __builtin_amdgcn_mfma_f32_16x16x32_bf16(
              af[i], bfr[j], acc[i][j], 0, 0, 0);
    }
  }

#pragma unroll
  for (int i = 0; i < 2; ++i) {
#pragma unroll
    for (int r = 0; r < 4; ++r) {
      const int m = m0 + wm + i * 16 + g * 4 + r;
#pragma unroll
      for (int j = 0; j < 4; ++j) {
        const int n = n0 + j * 16 + ln15;
        C[(size_t)m * N + n] = acc[i][j][r] + bias[n];
      }
    }
  }
}

// ---------------------------------------------------------------------------
// MFMA flash over COMPACTED query rows, r20: occupancy/latency restructure.
// 256-thread blocks (4 waves x 16 q-rows = 64 compacted rows), 64-col K/V
// tiles. LDS = Ks[64][68] + Vs[64][72] + Ps[64][68] = 26 KB -> 6 blocks/CU
// by LDS; grid (16, 64) with ~half active = 2-4 concurrent blocks/CU so one
// block's softmax (TRANS/VALU) overlaps another's MFMA. Math and summation
// order identical to r19 (64-col passes already existed as the t2 loop).
// ---------------------------------------------------------------------------
__global__ __launch_bounds__(256) void flash_mfma(
    const unsigned short* __restrict__ qkv, const unsigned short* __restrict__ vT,
    const unsigned short* __restrict__ cidx, const int* __restrict__ cntp,
    unsigned short* __restrict__ y) {
  __shared__ unsigned short Ks[64][68];    // K tokens x 64 dims (+4 pad)
  __shared__ unsigned short Vs[64][72];    // d-rows x 64 t-cols (+8 pad)
  __shared__ unsigned short Ps[64][68];

  const int tid = threadIdx.x;
  const int lane = tid & 63;
  const int wave = tid >> 6;              // 0..3
  const int ln15 = lane & 15;
  const int g = lane >> 4;
  const int bh = blockIdx.y;
  const int itile = (bh < 32) ? ((int)gridDim.x - 1 - (int)blockIdx.x)
                              : (int)blockIdx.x;   // balanced pairing
  const int b = bh >> 4;
  const int h = bh & 15;
  const int i0 = itile * 64;              // compacted-row tile base
  const int band = wave * 16;

  const int cnt = cntp[b];
  if (i0 >= cnt) return;                  // block-uniform early exit

  // original index of the block's last row -> K/V iteration count (64-col)
  const int omax_blk = cidx[b * TT + imin(i0 + 63, cnt - 1)];
  const int htiles = omax_blk / 64 + 1;

  const unsigned short* base = qkv + (size_t)b * TT * NQKV;
  const unsigned short* vbase = vT + (size_t)bh * DD * TT;  // rows d, cols t
  const int qoff = h * DD;
  const int koff = CC + h * DD;

  // staging coords: 256 threads, 64 rows x 128 B each for K and V
  const int ksn = tid >> 2;            // K token row 0..63
  const int kqc = (tid & 3) * 2;       // two 16-B chunks of the 128-B row
  const int vsn = tid >> 2;            // V d-row 0..63
  const int vqc = (tid & 3) * 2;

  // per-lane compacted slot -> original query row (clamped duplicates at tail)
  const int qslot = imin(i0 + band + ln15, cnt - 1);
  const int qorig = (int)cidx[b * TT + qslot];
  int oi_[4];
#pragma unroll
  for (int r = 0; r < 4; ++r) oi_[r] = __shfl(qorig, g * 4 + r, 16);
  const int obandmin = __shfl(qorig, 0, 16);
  const int obandmax = __shfl(qorig, 15, 16);

  bf16x8 qf[2];
  {
    const unsigned short* qp = base + (size_t)qorig * NQKV + qoff;
    qf[0] = *(const bf16x8*)(qp + g * 8);
    qf[1] = *(const bf16x8*)(qp + 32 + g * 8);
  }

  f32x4 accy[4] = {};           // y[m=g*4+r][d=dt*16+ln15] (unnormalized)
  float lrow[4] = {0.f, 0.f, 0.f, 0.f};

  // prefetch iteration 0
  float4 kr0, kr1, vr0, vr1;
  {
    const unsigned short* kp = base + (size_t)ksn * NQKV + koff + kqc * 8;
    const unsigned short* vp = vbase + (size_t)vsn * TT + vqc * 8;
    kr0 = *(const float4*)(kp + 0);
    kr1 = *(const float4*)(kp + 8);
    vr0 = *(const float4*)(vp + 0);
    vr1 = *(const float4*)(vp + 8);
  }

  for (int ht = 0; ht < htiles; ++ht) {
    const int j0 = ht * 64;
    __syncthreads();                       // prior-iter Ks/Vs consumers done
    *(float4*)&Ks[ksn][kqc * 8 + 0] = kr0;
    *(float4*)&Ks[ksn][kqc * 8 + 8] = kr1;
    *(float4*)&Vs[vsn][vqc * 8 + 0] = vr0;
    *(float4*)&Vs[vsn][vqc * 8 + 8] = vr1;
    __syncthreads();

    // prefetch next iteration (overlaps with compute below)
    if (ht + 1 < htiles) {
      const int j1 = j0 + 64;
      const unsigned short* kp = base + (size_t)(j1 + ksn) * NQKV + koff + kqc * 8;
      const unsigned short* vp = vbase + (size_t)vsn * TT + j1 + vqc * 8;
      kr0 = *(const float4*)(kp + 0);
      kr1 = *(const float4*)(kp + 8);
      vr0 = *(const float4*)(vp + 0);
      vr1 = *(const float4*)(vp + 8);
    }

    if (j0 <= obandmax) {                  // else fully masked for this band
      // S = Q . K^T
      f32x4 sf[4];
#pragma unroll
      for (int j = 0; j < 4; ++j) {
        const bf16x8 k0 = *(const bf16x8*)&Ks[j * 16 + ln15][g * 8];
        const bf16x8 k1 = *(const bf16x8*)&Ks[j * 16 + ln15][32 + g * 8];
        f32x4 z = {};
        z = __builtin_amdgcn_mfma_f32_16x16x32_bf16(qf[0], k0, z, 0, 0, 0);
        sf[j] = __builtin_amdgcn_mfma_f32_16x16x32_bf16(qf[1], k1, z, 0, 0, 0);
      }

      // p = exp2(-(ln2/8) * (log2(z)+1)^2);  ln2/8 = 0.08664339757
      float p[4][4];
      if (j0 + 63 <= obandmin) {
        // unmasked fast path (strictly at/below diagonal for all band rows)
#pragma unroll
        for (int j = 0; j < 4; ++j)
#pragma unroll
          for (int r = 0; r < 4; ++r) {
            const float l = hw_log2(fmaxf(sf[j][r], 1.0f));
            const float s = l + 1.0f;
            p[r][j] = hw_exp2(-0.08664339757f * s * s);
          }
      } else {
#pragma unroll
        for (int j = 0; j < 4; ++j) {
          const int gj = j0 + j * 16 + ln15;
#pragma unroll
          for (int r = 0; r < 4; ++r) {
            float e;
            if (gj > oi_[r]) {
              e = 0.f;
            } else {
              const float l = hw_log2(fmaxf(sf[j][r], 1.0f));
              const float s = l + 1.0f;
              e = hw_exp2(-0.08664339757f * s * s);
            }
            p[r][j] = e;
          }
        }
      }
#pragma unroll
      for (int r = 0; r < 4; ++r)
        lrow[r] += (p[r][0] + p[r][1]) + (p[r][2] + p[r][3]);

      // P -> LDS (bf16, A-layout); intra-wave producer/consumer, no barrier
#pragma unroll
      for (int r = 0; r < 4; ++r)
#pragma unroll
        for (int j = 0; j < 4; ++j)
          Ps[band + g * 4 + r][j * 16 + ln15] = f2b(p[r][j]);

      const bf16x8 pa0 = *(const bf16x8*)&Ps[band + ln15][g * 8];
      const bf16x8 pa1 = *(const bf16x8*)&Ps[band + ln15][32 + g * 8];
#pragma unroll
      for (int dt = 0; dt < 4; ++dt) {
        const bf16x8 v0 = *(const bf16x8*)&Vs[dt * 16 + ln15][g * 8];
        const bf16x8 v1 = *(const bf16x8*)&Vs[dt * 16 + ln15][32 + g * 8];
        accy[dt] = __builtin_amdgcn_mfma_f32_16x16x32_bf16(pa0, v0, accy[dt], 0, 0, 0);
        accy[dt] = __builtin_amdgcn_mfma_f32_16x16x32_bf16(pa1, v1, accy[dt], 0, 0, 0);
      }
    }
  }

  // epilogue: reduce lrow across the 16 n-lanes, scale, scatter-store
#pragma unroll
  for (int r = 0; r < 4; ++r) {
#pragma unroll
    for (int off = 1; off < 16; off <<= 1)
      lrow[r] += __shfl_xor(lrow[r], off, 64);
  }
#pragma unroll
  for (int r = 0; r < 4; ++r) {
    const int slot = i0 + band + g * 4 + r;
    if (slot < cnt) {                      // guard tail duplicates
      const float scale = 1.0f / lrow[r];  // surviving rows: spike == 1
      const size_t yrow = (size_t)(b * TT + oi_[r]);
#pragma unroll
      for (int dt = 0; dt < 4; ++dt)
        y[yrow * CC + h * DD + dt * 16 + ln15] = f2b(accy[dt][r] * scale);
    }
  }
}

// ---------------------------------------------------------------------------
extern "C" void kernel_launch(void* const* d_in, const int* in_sizes, int n_in,
                              void* d_out, int out_size, void* d_ws, size_t ws_size,
                              hipStream_t stream) {
  const float* x     = (const float*)d_in[0];
  const float* W_qkv = (const float*)d_in[1];
  const float* b_qkv = (const float*)d_in[2];
  const float* W_out = (const float*)d_in[3];
  const float* b_out = (const float*)d_in[4];
  const float* w_sur = (const float*)d_in[5];
  const float* b_sur = (const float*)d_in[6];
  const float* thr   = (const float*)d_in[7];
  float* out = (float*)d_out;

  // ws layout (bytes):
  //   xb 8.39M | qkvb 25.17M | vT 8.39M | ybufb 8.39M | WqkvT 6.29M |
  //   WoutT 2.10M | spikes 16K | cidx 8K | count 16B
  char* w = (char*)d_ws;
  unsigned short* xb    = (unsigned short*)(w);
  unsigned short* qkvb  = (unsigned short*)(w + 8388608);
  unsigned short* vTb   = (unsigned short*)(w + 8388608 + 25165824);
  unsigned short* ybufb = (unsigned short*)(w + 8388608 + 25165824 + 8388608);
  unsigned short* WqkvT = (unsigned short*)(w + 8388608 + 25165824 + 2 * 8388608);
  unsigned short* WoutT = (unsigned short*)(w + 8388608 + 25165824 + 2 * 8388608 + 6291456);
  float* spikes = (float*)(w + 58720256);
  unsigned short* cidx = (unsigned short*)(w + 58720256 + 16384);
  int* cnt = (int*)(w + 58720256 + 16384 + 8192);

  prep<<<5120, 256, 0, stream>>>(x, w_sur, b_sur, thr, W_qkv, W_out,
                                 spikes, xb, WqkvT, WoutT, ybufb);

  compact<<<4, 1024, 0, stream>>>(spikes, cidx, cnt);

  gemm_qkv<<<dim3(NQKV / 128, MROWS / 128), 256, 0, stream>>>(
      xb, WqkvT, b_qkv, qkvb, vTb);

  flash_mfma<<<dim3(TT / 64, BB * HH), 256, 0, stream>>>(qkvb, vTb, cidx, cnt, ybufb);

  gemm_out<<<dim3(CC / 64, MROWS / 128), 256, 0, stream>>>(
      ybufb, WoutT, b_out, out);
}

// Round 6
// 173.583 us; speedup vs baseline: 1.0412x; 1.0046x over previous
//
#include <hip/hip_runtime.h>
#include <math.h>

// Problem dims (fixed)
#define BB 4
#define TT 1024
#define CC 1024
#define HH 16
#define DD 64
#define NQKV (3 * CC)      // 3072
#define MROWS (BB * TT)    // 4096

typedef __attribute__((ext_vector_type(8))) short bf16x8;   // 8 bf16 (4 VGPRs)
typedef __attribute__((ext_vector_type(4))) float f32x4;    // MFMA C/D

struct alignas(8) US4 { unsigned short x, y, z, w; };

__device__ __forceinline__ float b2f(unsigned short u) {
  unsigned int w = ((unsigned int)u) << 16;
  float f; __builtin_memcpy(&f, &w, 4); return f;
}
__device__ __forceinline__ unsigned short f2b(float f) {
  unsigned int u; __builtin_memcpy(&u, &f, 4);
  u += 0x7FFFu + ((u >> 16) & 1);        // RNE
  return (unsigned short)(u >> 16);
}

// raw hardware transcendentals: v_log_f32 (log2), v_exp_f32 (2^x)
__device__ __forceinline__ float hw_log2(float x) {
  return __builtin_amdgcn_logf(x);
}
__device__ __forceinline__ float hw_exp2(float x) {
  return __builtin_amdgcn_exp2f(x);
}

// async global->LDS, 16 B per lane; lds dest is wave-uniform base + lane*16
__device__ __forceinline__ void gload16(const void* g, void* l) {
  __builtin_amdgcn_global_load_lds(
      (const __attribute__((address_space(1))) unsigned int*)g,
      (__attribute__((address_space(3))) unsigned int*)l, 16, 0, 0);
}

// swizzled frag read: row_base points at a 128-B LDS row; logical 16-B chunk
// lc is stored at physical chunk lc ^ (row & 7).
__device__ __forceinline__ bf16x8 ld_sw(const unsigned short* row_base,
                                        int lc, int rsw) {
  return *(const bf16x8*)((const char*)row_base + (((lc ^ rsw) & 7) << 4));
}

// ---------------------------------------------------------------------------
// PREP (verified r13): one launch = W_qkv transpose | W_out transpose |
// spike flags + x->bf16.
// ---------------------------------------------------------------------------
__global__ __launch_bounds__(256) void prep(
    const float* __restrict__ x, const float* __restrict__ w_sur,
    const float* __restrict__ b_sur, const float* __restrict__ thr,
    const float* __restrict__ W_qkv, const float* __restrict__ W_out,
    float* __restrict__ spikes, unsigned short* __restrict__ xb,
    unsigned short* __restrict__ WqkvT, unsigned short* __restrict__ WoutT) {
  __shared__ float t[32][33];
  const int blk = blockIdx.x;

  if (blk < 4096) {
    const float* W; unsigned short* WT; int K, N, bx, by;
    if (blk < 3072) {
      W = W_qkv; WT = WqkvT; K = CC; N = NQKV;
      bx = blk % 96; by = blk / 96;
    } else {
      W = W_out; WT = WoutT; K = CC; N = CC;
      const int b2 = blk - 3072;
      bx = b2 & 31; by = b2 >> 5;
    }
    const int tx = threadIdx.x & 31, ty = threadIdx.x >> 5;
    const int k0 = by * 32, n0 = bx * 32;
#pragma unroll
    for (int i = 0; i < 32; i += 8)
      t[ty + i][tx] = W[(size_t)(k0 + ty + i) * N + n0 + tx];
    __syncthreads();
#pragma unroll
    for (int i = 0; i < 32; i += 8)
      WT[(size_t)(n0 + ty + i) * K + k0 + tx] = f2b(t[tx][ty + i]);
  } else {
    const int row = (blk - 4096) * 4 + (threadIdx.x >> 6);
    const int lane = threadIdx.x & 63;
    const float* xr = x + (size_t)row * CC;
    unsigned short* xo = xb + (size_t)row * CC;
    double acc = 0.0;
#pragma unroll
    for (int s = 0; s < 4; ++s) {
      const int idx = s * 256 + lane * 4;
      const float4 xv = *(const float4*)(xr + idx);
      const float4 wv = *(const float4*)(w_sur + idx);
      acc += (double)xv.x * (double)wv.x;
      acc += (double)xv.y * (double)wv.y;
      acc += (double)xv.z * (double)wv.z;
      acc += (double)xv.w * (double)wv.w;
      US4 o = {f2b(xv.x), f2b(xv.y), f2b(xv.z), f2b(xv.w)};
      *(US4*)(xo + idx) = o;
    }
#pragma unroll
    for (int off = 32; off > 0; off >>= 1) acc += __shfl_xor(acc, off, 64);
    if (lane == 0) {
      const float z = (float)acc + b_sur[0];
      const float imp = 1.0f / (1.0f + __expf(-z));
      spikes[row] = (imp > thr[0]) ? 1.0f : 0.0f;
    }
  }
}

// ---------------------------------------------------------------------------
// QKV GEMM + fused Lorentz + fused V-transpose.
// r21: 256x256 tile, 8 waves (2 row x 4 col, 128x64 output each), BK=64,
// double-buffered K-tiles in LDS (2 x 64 KB), 4 MFMA-phases per K-tile:
// each phase = {ds_read A-frags (+B frags at p0), issue 1/2 of next-tile
// staging at p0/p1, setprio(1), 16 MFMA, setprio(0), s_barrier}. One
// __syncthreads drain per K-tile; staging issued 2-4 phases before the
// drain so global latency is covered by MFMA. XOR chunk swizzle on both
// sides (verified r15 pattern). Epilogue: same r18 Lorentz / V-transpose
// math with M_rep=8, per-wave 16 KB scratch (128 KB LDS reuse).
// ---------------------------------------------------------------------------
__global__ __launch_bounds__(512, 2) void gemm_qkv(
    const unsigned short* __restrict__ A, const unsigned short* __restrict__ BT,
    const float* __restrict__ bias, unsigned short* __restrict__ qkvb,
    unsigned short* __restrict__ vT) {
  const int K = CC;
  __shared__ unsigned short SH[65536];     // 128 KB: A0|A1|B0|B1 (32 KB each)
  const int tid = threadIdx.x;
  const int lane = tid & 63;
  const int wave = tid >> 6;               // 0..7
  const int wr = wave >> 2;                // wave row 0..1 (128 rows each)
  const int wc = wave & 3;                 // wave col 0..3 (64 cols each)
  const int m0 = blockIdx.y * 256;
  const int n0 = blockIdx.x * 256;
  const int ln15 = lane & 15;
  const int g = lane >> 4;
  const int rsw = ln15 & 7;                // frag-read swizzle key

  // staging coords: 512 threads x 16 B = one 64-row group (8 KB) per issue
  const int srow = tid >> 3;               // 0..63
  const int schk = ((tid & 7) ^ (srow & 7)) * 8;   // swizzled fetch chunk
  const unsigned short* gA = A + (size_t)(m0 + srow) * K + schk;
  const unsigned short* gB = BT + (size_t)(n0 + srow) * K + schk;
  char* lbase = (char*)SH;
  const int wave1k = wave * 1024;

  f32x4 acc[8][4] = {};

  // prologue: stage K-tile 0 into buffer 0 (A 4 groups + B 4 groups)
#pragma unroll
  for (int g64 = 0; g64 < 4; ++g64)
    gload16(gA + (size_t)(g64 * 64) * K, lbase + g64 * 8192 + wave1k);
#pragma unroll
  for (int g64 = 0; g64 < 4; ++g64)
    gload16(gB + (size_t)(g64 * 64) * K, lbase + 65536 + g64 * 8192 + wave1k);
  __syncthreads();

  for (int kt = 0; kt < 16; ++kt) {
    const unsigned short* As = SH + (kt & 1) * 16384;
    const unsigned short* Bs = SH + 32768 + (kt & 1) * 16384;
    const int nd = (kt + 1) & 1;
    const bool more = (kt + 1 < 16);
    const int kc = (kt + 1) * 64;

    bf16x8 bfr[4][2];
#pragma unroll
    for (int p = 0; p < 4; ++p) {
      // staging: p0 -> next A tile (4 groups), p1 -> next B tile (4 groups)
      if (p == 0 && more) {
#pragma unroll
        for (int g64 = 0; g64 < 4; ++g64)
          gload16(gA + (size_t)(g64 * 64) * K + kc,
                  lbase + nd * 32768 + g64 * 8192 + wave1k);
      }
      if (p == 1 && more) {
#pragma unroll
        for (int g64 = 0; g64 < 4; ++g64)
          gload16(gB + (size_t)(g64 * 64) * K + kc,
                  lbase + 65536 + nd * 32768 + g64 * 8192 + wave1k);
      }
      // B fragments for the whole K-tile, read once at p0
      if (p == 0) {
#pragma unroll
        for (int j = 0; j < 4; ++j)
#pragma unroll
          for (int c = 0; c < 2; ++c)
            bfr[j][c] = ld_sw(Bs + (wc * 64 + j * 16 + ln15) * 64, c * 4 + g, rsw);
      }
      // A fragments for this phase's two row-blocks
      bf16x8 af[2][2];
#pragma unroll
      for (int ii = 0; ii < 2; ++ii)
#pragma unroll
        for (int c = 0; c < 2; ++c)
          af[ii][c] = ld_sw(As + (wr * 128 + (p * 2 + ii) * 16 + ln15) * 64,
                            c * 4 + g, rsw);

      __builtin_amdgcn_s_setprio(1);
#pragma unroll
      for (int ii = 0; ii < 2; ++ii)
#pragma unroll
        for (int j = 0; j < 4; ++j)
#pragma unroll
          for (int c = 0; c < 2; ++c)
            acc[p * 2 + ii][j] = __builtin_amdgcn_mfma_f32_16x16x32_bf16(
                af[ii][c], bfr[j][c], acc[p * 2 + ii][j], 0, 0, 0);
      __builtin_amdgcn_s_setprio(0);
      __builtin_amdgcn_sched_barrier(0);
      __builtin_amdgcn_s_barrier();
    }
    __syncthreads();   // drain: next tile landed; this tile's reads done
  }

  // ---- epilogue: per-wave 16 KB scratch region of SH ----
  unsigned short* scr = SH + wave * 8192;

  const int bx = blockIdx.x;               // segment: q<4, k<8, v else
  if (bx < 8) {
    const bool isk = (bx >= 4);
#pragma unroll
    for (int i = 0; i < 8; ++i) {
#pragma unroll
      for (int r = 0; r < 4; ++r) {
        float u[4];
        float part = 0.f;
#pragma unroll
        for (int j = 0; j < 4; ++j) {
          u[j] = acc[i][j][r] + bias[n0 + wc * 64 + j * 16 + ln15];
          float sq = u[j] * u[j];
          if (j == 0 && ln15 == 0) sq = -sq;     // time component
          part += sq;
        }
#pragma unroll
        for (int off = 1; off < 16; off <<= 1)
          part += __shfl_xor(part, off, 64);
        const float nomin = sqrtf(fmaxf(part, 1e-8f));
        const float e = __expf(nomin);
        const float ei = __builtin_amdgcn_rcpf(e);
        const float tim = 0.5f * (e + ei);
        const float coef = 0.5f * (e - ei) * __builtin_amdgcn_rcpf(nomin);
        const int lrow = i * 16 + g * 4 + r;     // token-local 0..127
#pragma unroll
        for (int j = 0; j < 4; ++j) {
          float o = (j == 0 && ln15 == 0) ? tim : coef * u[j];
          if (isk && !(j == 0 && ln15 == 0)) o = -o;
          const int col = j * 16 + ln15;
          const int ch = ((col >> 3) + lrow) & 7;
          scr[lrow * 64 + ch * 8 + (col & 7)] = f2b(o);
        }
      }
    }
#pragma unroll
    for (int it = 0; it < 16; ++it) {
      const int row = (lane >> 3) + 8 * it;    // 0..127
      const int ch = lane & 7;
      const int ph = (ch + row) & 7;
      const bf16x8 v = *(const bf16x8*)&scr[row * 64 + ph * 8];
      *(bf16x8*)&qkvb[(size_t)(m0 + wr * 128 + row) * NQKV + n0 + wc * 64 + ch * 8] = v;
    }
  } else {
    // V segment: transpose to vT[d][t]; scratch 64 d-rows x 128 t-cols
#pragma unroll
    for (int i = 0; i < 8; ++i) {
#pragma unroll
      for (int j = 0; j < 4; ++j) {
        const float bb_ = bias[n0 + wc * 64 + j * 16 + ln15];
        const int drow = j * 16 + ln15;          // 0..63
#pragma unroll
        for (int r = 0; r < 4; ++r) {
          const int col = i * 16 + g * 4 + r;    // t-local 0..127
          const int ch = ((col >> 3) + drow) & 15;
          scr[drow * 128 + ch * 8 + (col & 7)] = f2b(acc[i][j][r] + bb_);
        }
      }
    }
    const int hh = (bx - 8) * 4 + wc;
    const int mbase = m0 + wr * 128;
    const int bq = mbase >> 10;
    const int t0 = mbase & 1023;
#pragma unroll
    for (int it = 0; it < 16; ++it) {
      const int drow = (lane >> 4) + 4 * it;   // 0..63
      const int chunk = lane & 15;             // 16 chunks of the 256-B row
      const int ph = (chunk + drow) & 15;
      const bf16x8 v = *(const bf16x8*)&scr[drow * 128 + ph * 8];
      *(bf16x8*)&vT[((size_t)(bq * HH + hh) * DD + drow) * TT + t0 + chunk * 8] = v;
    }
  }
}

// ---------------------------------------------------------------------------
// Out GEMM (verified r15): 128x64 tiles, 2/CU, XOR chunk swizzle.
// ---------------------------------------------------------------------------
__global__ __launch_bounds__(256) void gemm_out(
    const unsigned short* __restrict__ A, const unsigned short* __restrict__ BT,
    const float* __restrict__ bias, float* __restrict__ C) {
  const int N = CC, K = CC;
  __shared__ unsigned short As[128][64];   // 16 KB
  __shared__ unsigned short Bs[64][64];    // 8 KB
  const int tid = threadIdx.x;
  const int lane = tid & 63;
  const int wave = tid >> 6;
  const int wm = wave * 32;
  const int m0 = blockIdx.y * 128;
  const int n0 = blockIdx.x * 64;
  const int ln15 = lane & 15;
  const int g = lane >> 4;
  const int rsw = ln15 & 7;

  const int srow = tid >> 3;           // 0..31
  const int schk = ((tid & 7) ^ (srow & 7)) * 8;
  const unsigned short* gA = A + (size_t)(m0 + srow) * K + schk;
  const unsigned short* gB = BT + (size_t)(n0 + srow) * K + schk;
  char* lA = (char*)As + wave * 1024;
  char* lB = (char*)Bs + wave * 1024;

  f32x4 acc[2][4] = {};

  for (int k0 = 0; k0 < K; k0 += 64) {
    __syncthreads();
#pragma unroll
    for (int i = 0; i < 4; ++i)
      gload16(gA + k0 + (size_t)(32 * i) * K, lA + i * 4096);
#pragma unroll
    for (int i = 0; i < 2; ++i)
      gload16(gB + k0 + (size_t)(32 * i) * K, lB + i * 4096);
    __syncthreads();

#pragma unroll
    for (int c = 0; c < 2; ++c) {
      bf16x8 af[2], bfr[4];
#pragma unroll
      for (int i = 0; i < 2; ++i)
        af[i] = ld_sw(&As[wm + i * 16 + ln15][0], c * 4 + g, rsw);
#pragma unroll
      for (int j = 0; j < 4; ++j)
        bfr[j] = ld_sw(&Bs[j * 16 + ln15][0], c * 4 + g, rsw);
#pragma unroll
      for (int i = 0; i < 2; ++i)
#pragma unroll
        for (int j = 0; j < 4; ++j)
          acc[i][j] = __builtin_amdgcn_mfma_f32_16x16x32_bf16(
              af[i], bfr[j], acc[i][j], 0, 0, 0);
    }
  }

#pragma unroll
  for (int i = 0; i < 2; ++i) {
#pragma unroll
    for (int r = 0; r < 4; ++r) {
      const int m = m0 + wm + i * 16 + g * 4 + r;
#pragma unroll
      for (int j = 0; j < 4; ++j) {
        const int n = n0 + j * 16 + ln15;
        C[(size_t)m * N + n] = acc[i][j][r] + bias[n];
      }
    }
  }
}

// ---------------------------------------------------------------------------
// MFMA flash, 128-row Q blocks (verified r17/r18).
// ---------------------------------------------------------------------------
__global__ __launch_bounds__(512) void flash_mfma(
    const unsigned short* __restrict__ qkv, const unsigned short* __restrict__ vT,
    const float* __restrict__ spikes, unsigned short* __restrict__ y) {
  __shared__ unsigned short Ks[128][68];
  __shared__ unsigned short Vs[64][136];   // Vs[d][t-local 0..127]
  __shared__ unsigned short Ps[128][68];

  const int tid = threadIdx.x;
  const int lane = tid & 63;
  const int wave = tid >> 6;              // 0..7
  const int ln15 = lane & 15;
  const int g = lane >> 4;
  const int bh = blockIdx.y;
  const int itile = (bh < 32) ? ((int)gridDim.x - 1 - (int)blockIdx.x)
                              : (int)blockIdx.x;   // balanced pairing
  const int b = bh >> 4;
  const int h = bh & 15;
  const int i0 = itile * 128;
  const int band = wave * 16;
  const int htiles = itile + 1;           // 128-col iterations
  const unsigned short* base = qkv + (size_t)b * TT * NQKV;
  const unsigned short* vbase = vT + (size_t)bh * DD * TT;  // rows d, cols t
  const int qoff = h * DD;
  const int koff = CC + h * DD;

  // staging coords
  const int ksn = tid >> 2;            // K row 0..127
  const int kqc = (tid & 3) * 2;       // two 16-B chunks of the 128-B row
  const int vsn = tid >> 3;            // V d-row 0..63
  const int vqc = (tid & 7) * 2;       // two 16-B chunks of the 256-B row

  bf16x8 qf[2];
  {
    const unsigned short* qp = base + (size_t)(i0 + band + ln15) * NQKV + qoff;
    qf[0] = *(const bf16x8*)(qp + g * 8);
    qf[1] = *(const bf16x8*)(qp + 32 + g * 8);
  }

  f32x4 accy[4] = {};           // y[m=g*4+r][d=dt*16+ln15] (unnormalized)
  float lrow[4] = {0.f, 0.f, 0.f, 0.f};

  // prefetch iteration 0
  float4 kr0, kr1, vr0, vr1;
  {
    const unsigned short* kp = base + (size_t)ksn * NQKV + koff + kqc * 8;
    const unsigned short* vp = vbase + (size_t)vsn * TT + vqc * 8;
    kr0 = *(const float4*)(kp + 0);
    kr1 = *(const float4*)(kp + 8);
    vr0 = *(const float4*)(vp + 0);
    vr1 = *(const float4*)(vp + 8);
  }

  for (int ht = 0; ht < htiles; ++ht) {
    const int j0h = ht * 128;
    __syncthreads();                       // prior-iter Ks/Vs consumers done
    *(float4*)&Ks[ksn][kqc * 8 + 0] = kr0;
    *(float4*)&Ks[ksn][kqc * 8 + 8] = kr1;
    *(float4*)&Vs[vsn][vqc * 8 + 0] = vr0;
    *(float4*)&Vs[vsn][vqc * 8 + 8] = vr1;
    __syncthreads();

    // prefetch next iteration (overlaps with compute below)
    if (ht + 1 < htiles) {
      const int j1 = j0h + 128;
      const unsigned short* kp = base + (size_t)(j1 + ksn) * NQKV + koff + kqc * 8;
      const unsigned short* vp = vbase + (size_t)vsn * TT + j1 + vqc * 8;
      kr0 = *(const float4*)(kp + 0);
      kr1 = *(const float4*)(kp + 8);
      vr0 = *(const float4*)(vp + 0);
      vr1 = *(const float4*)(vp + 8);
    }

#pragma unroll
    for (int t2 = 0; t2 < 2; ++t2) {
      const int j0 = j0h + t2 * 64;
      if (j0 > i0 + band + 15) continue;   // fully masked for this band

      // S = Q . K^T  (K rows t2*64 .. +63)
      f32x4 sf[4];
#pragma unroll
      for (int j = 0; j < 4; ++j) {
        const bf16x8 k0 = *(const bf16x8*)&Ks[t2 * 64 + j * 16 + ln15][g * 8];
        const bf16x8 k1 = *(const bf16x8*)&Ks[t2 * 64 + j * 16 + ln15][32 + g * 8];
        f32x4 z = {};
        z = __builtin_amdgcn_mfma_f32_16x16x32_bf16(qf[0], k0, z, 0, 0, 0);
        sf[j] = __builtin_amdgcn_mfma_f32_16x16x32_bf16(qf[1], k1, z, 0, 0, 0);
      }

      // p = exp2(-(ln2/8) * (log2(z)+1)^2);  ln2/8 = 0.08664339757
      float p[4][4];
      if (j0 + 63 <= i0 + band) {
        // unmasked fast path (strictly below diagonal for this wave)
#pragma unroll
        for (int j = 0; j < 4; ++j)
#pragma unroll
          for (int r = 0; r < 4; ++r) {
            const float l = hw_log2(fmaxf(sf[j][r], 1.0f));
            const float s = l + 1.0f;
            p[r][j] = hw_exp2(-0.08664339757f * s * s);
          }
      } else {
#pragma unroll
        for (int j = 0; j < 4; ++j) {
          const int gj = j0 + j * 16 + ln15;
#pragma unroll
          for (int r = 0; r < 4; ++r) {
            const int gi = i0 + band + g * 4 + r;
            float e;
            if (gj > gi) {
              e = 0.f;
            } else {
              const float l = hw_log2(fmaxf(sf[j][r], 1.0f));
              const float s = l + 1.0f;
              e = hw_exp2(-0.08664339757f * s * s);
            }
            p[r][j] = e;
          }
        }
      }
#pragma unroll
      for (int r = 0; r < 4; ++r)
        lrow[r] += (p[r][0] + p[r][1]) + (p[r][2] + p[r][3]);

      // P -> LDS (bf16, A-layout); intra-wave producer/consumer, no barrier
#pragma unroll
      for (int r = 0; r < 4; ++r)
#pragma unroll
        for (int j = 0; j < 4; ++j)
          Ps[band + g * 4 + r][j * 16 + ln15] = f2b(p[r][j]);

      const bf16x8 pa0 = *(const bf16x8*)&Ps[band + ln15][g * 8];
      const bf16x8 pa1 = *(const bf16x8*)&Ps[band + ln15][32 + g * 8];
#pragma unroll
      for (int dt = 0; dt < 4; ++dt) {
        const bf16x8 v0 = *(const bf16x8*)&Vs[dt * 16 + ln15][t2 * 64 + g * 8];
        const bf16x8 v1 = *(const bf16x8*)&Vs[dt * 16 + ln15][t2 * 64 + 32 + g * 8];
        accy[dt] = __builtin_amdgcn_mfma_f32_16x16x32_bf16(pa0, v0, accy[dt], 0, 0, 0);
        accy[dt] = __builtin_amdgcn_mfma_f32_16x16x32_bf16(pa1, v1, accy[dt], 0, 0, 0);
      }
    }
  }

  // epilogue: reduce lrow across the 16 n-lanes, scale, store
#pragma unroll
  for (int r = 0; r < 4; ++r) {
#pragma unroll
    for (int off = 1; off < 16; off <<= 1)
      lrow[r] += __shfl_xor(lrow[r], off, 64);
  }
  const int grow = b * TT + i0 + band + g * 4;
#pragma unroll
  for (int r = 0; r < 4; ++r) {
    const float spk = spikes[grow + r];
    const float scale = spk / lrow[r];
#pragma unroll
    for (int dt = 0; dt < 4; ++dt)
      y[(size_t)(grow + r) * CC + h * DD + dt * 16 + ln15] =
          f2b(accy[dt][r] * scale);
  }
}

// ---------------------------------------------------------------------------
extern "C" void kernel_launch(void* const* d_in, const int* in_sizes, int n_in,
                              void* d_out, int out_size, void* d_ws, size_t ws_size,
                              hipStream_t stream) {
  const float* x     = (const float*)d_in[0];
  const float* W_qkv = (const float*)d_in[1];
  const float* b_qkv = (const float*)d_in[2];
  const float* W_out = (const float*)d_in[3];
  const float* b_out = (const float*)d_in[4];
  const float* w_sur = (const float*)d_in[5];
  const float* b_sur = (const float*)d_in[6];
  const float* thr   = (const float*)d_in[7];
  float* out = (float*)d_out;

  // ws layout (bytes, total ~58.8 MB):
  //   xb 8.39M | qkvb 25.17M | vT 8.39M | ybufb 8.39M | WqkvT 6.29M |
  //   WoutT 2.10M | spikes 16K
  char* w = (char*)d_ws;
  unsigned short* xb    = (unsigned short*)(w);
  unsigned short* qkvb  = (unsigned short*)(w + 8388608);
  unsigned short* vTb   = (unsigned short*)(w + 8388608 + 25165824);
  unsigned short* ybufb = (unsigned short*)(w + 8388608 + 25165824 + 8388608);
  unsigned short* WqkvT = (unsigned short*)(w + 8388608 + 25165824 + 2 * 8388608);
  unsigned short* WoutT = (unsigned short*)(w + 8388608 + 25165824 + 2 * 8388608 + 6291456);
  float* spikes = (float*)(w + 8388608 + 25165824 + 2 * 8388608 + 6291456 + 2097152);

  prep<<<5120, 256, 0, stream>>>(x, w_sur, b_sur, thr, W_qkv, W_out,
                                 spikes, xb, WqkvT, WoutT);

  gemm_qkv<<<dim3(NQKV / 256, MROWS / 256), 512, 0, stream>>>(
      xb, WqkvT, b_qkv, qkvb, vTb);

  flash_mfma<<<dim3(TT / 128, BB * HH), 512, 0, stream>>>(qkvb, vTb, spikes, ybufb);

  gemm_out<<<dim3(CC / 64, MROWS / 128), 256, 0, stream>>>(
      ybufb, WoutT, b_out, out);
}

// Round 7
// 164.607 us; speedup vs baseline: 1.0980x; 1.0545x over previous
//
#include <hip/hip_runtime.h>
#include <math.h>

// Problem dims (fixed)
#define BB 4
#define TT 1024
#define CC 1024
#define HH 16
#define DD 64
#define NQKV (3 * CC)      // 3072
#define MROWS (BB * TT)    // 4096

typedef __attribute__((ext_vector_type(8))) short bf16x8;   // 8 bf16 (4 VGPRs)
typedef __attribute__((ext_vector_type(4))) float f32x4;    // MFMA C/D

struct alignas(8) US4 { unsigned short x, y, z, w; };

__device__ __forceinline__ float b2f(unsigned short u) {
  unsigned int w = ((unsigned int)u) << 16;
  float f; __builtin_memcpy(&f, &w, 4); return f;
}
__device__ __forceinline__ unsigned short f2b(float f) {
  unsigned int u; __builtin_memcpy(&u, &f, 4);
  u += 0x7FFFu + ((u >> 16) & 1);        // RNE
  return (unsigned short)(u >> 16);
}

// raw hardware transcendentals: v_log_f32 (log2), v_exp_f32 (2^x)
__device__ __forceinline__ float hw_log2(float x) {
  return __builtin_amdgcn_logf(x);
}
__device__ __forceinline__ float hw_exp2(float x) {
  return __builtin_amdgcn_exp2f(x);
}

// async global->LDS, 16 B per lane; lds dest is wave-uniform base + lane*16
__device__ __forceinline__ void gload16(const void* g, void* l) {
  __builtin_amdgcn_global_load_lds(
      (const __attribute__((address_space(1))) unsigned int*)g,
      (__attribute__((address_space(3))) unsigned int*)l, 16, 0, 0);
}

// swizzled frag read: row_base points at a 128-B LDS row; logical 16-B chunk
// lc is stored at physical chunk lc ^ (row & 7).
__device__ __forceinline__ bf16x8 ld_sw(const unsigned short* row_base,
                                        int lc, int rsw) {
  return *(const bf16x8*)((const char*)row_base + (((lc ^ rsw) & 7) << 4));
}

// ---------------------------------------------------------------------------
// PREP (verified r13): one launch = W_qkv transpose | W_out transpose |
// spike flags + x->bf16.
// ---------------------------------------------------------------------------
__global__ __launch_bounds__(256) void prep(
    const float* __restrict__ x, const float* __restrict__ w_sur,
    const float* __restrict__ b_sur, const float* __restrict__ thr,
    const float* __restrict__ W_qkv, const float* __restrict__ W_out,
    float* __restrict__ spikes, unsigned short* __restrict__ xb,
    unsigned short* __restrict__ WqkvT, unsigned short* __restrict__ WoutT) {
  __shared__ float t[32][33];
  const int blk = blockIdx.x;

  if (blk < 4096) {
    const float* W; unsigned short* WT; int K, N, bx, by;
    if (blk < 3072) {
      W = W_qkv; WT = WqkvT; K = CC; N = NQKV;
      bx = blk % 96; by = blk / 96;
    } else {
      W = W_out; WT = WoutT; K = CC; N = CC;
      const int b2 = blk - 3072;
      bx = b2 & 31; by = b2 >> 5;
    }
    const int tx = threadIdx.x & 31, ty = threadIdx.x >> 5;
    const int k0 = by * 32, n0 = bx * 32;
#pragma unroll
    for (int i = 0; i < 32; i += 8)
      t[ty + i][tx] = W[(size_t)(k0 + ty + i) * N + n0 + tx];
    __syncthreads();
#pragma unroll
    for (int i = 0; i < 32; i += 8)
      WT[(size_t)(n0 + ty + i) * K + k0 + tx] = f2b(t[tx][ty + i]);
  } else {
    const int row = (blk - 4096) * 4 + (threadIdx.x >> 6);
    const int lane = threadIdx.x & 63;
    const float* xr = x + (size_t)row * CC;
    unsigned short* xo = xb + (size_t)row * CC;
    double acc = 0.0;
#pragma unroll
    for (int s = 0; s < 4; ++s) {
      const int idx = s * 256 + lane * 4;
      const float4 xv = *(const float4*)(xr + idx);
      const float4 wv = *(const float4*)(w_sur + idx);
      acc += (double)xv.x * (double)wv.x;
      acc += (double)xv.y * (double)wv.y;
      acc += (double)xv.z * (double)wv.z;
      acc += (double)xv.w * (double)wv.w;
      US4 o = {f2b(xv.x), f2b(xv.y), f2b(xv.z), f2b(xv.w)};
      *(US4*)(xo + idx) = o;
    }
#pragma unroll
    for (int off = 32; off > 0; off >>= 1) acc += __shfl_xor(acc, off, 64);
    if (lane == 0) {
      const float z = (float)acc + b_sur[0];
      const float imp = 1.0f / (1.0f + __expf(-z));
      spikes[row] = (imp > thr[0]) ? 1.0f : 0.0f;
    }
  }
}

// ---------------------------------------------------------------------------
// QKV GEMM + fused Lorentz + fused V-transpose.
// r18 (verified 168.4): 128x128 tile, 2x2 waves x 64x64 output each,
// 32 MFMA : 16 ds_read_b128 per K-step, 768 blocks = 3/CU pinned via
// __launch_bounds__(256,3). Each wave's 64-col span is exactly one head.
// LDS: As 128x64 | Bs 128x64 = 32 KB (epilogue reuses as 4 x 8 KB scratch).
// ---------------------------------------------------------------------------
__global__ __launch_bounds__(256, 3) void gemm_qkv(
    const unsigned short* __restrict__ A, const unsigned short* __restrict__ BT,
    const float* __restrict__ bias, unsigned short* __restrict__ qkvb,
    unsigned short* __restrict__ vT) {
  const int K = CC;
  __shared__ unsigned short SH[16384];     // 32 KB: As 128x64 | Bs 128x64
  unsigned short (*As)[64] = (unsigned short(*)[64])SH;
  unsigned short (*Bs)[64] = (unsigned short(*)[64])(SH + 8192);
  const int tid = threadIdx.x;
  const int lane = tid & 63;
  const int wave = tid >> 6;
  const int wr = wave >> 1;            // wave row 0..1 (64 rows each)
  const int wc = wave & 1;             // wave col 0..1 (64 cols each)
  const int m0 = blockIdx.y * 128;
  const int n0 = blockIdx.x * 128;
  const int ln15 = lane & 15;
  const int g = lane >> 4;
  const int rsw = ln15 & 7;            // frag-read swizzle key

  const int srow = tid >> 3;           // 0..31
  const int schk = ((tid & 7) ^ (srow & 7)) * 8;   // swizzled fetch chunk
  const unsigned short* gA = A + (size_t)(m0 + srow) * K + schk;
  const unsigned short* gB = BT + (size_t)(n0 + srow) * K + schk;
  char* lA = (char*)SH + wave * 1024;
  char* lB = (char*)SH + 16384 + wave * 1024;

  f32x4 acc[4][4] = {};

  for (int k0 = 0; k0 < K; k0 += 64) {
    __syncthreads();
#pragma unroll
    for (int i = 0; i < 4; ++i)
      gload16(gA + k0 + (size_t)(32 * i) * K, lA + i * 4096);
#pragma unroll
    for (int i = 0; i < 4; ++i)
      gload16(gB + k0 + (size_t)(32 * i) * K, lB + i * 4096);
    __syncthreads();

#pragma unroll
    for (int c = 0; c < 2; ++c) {
      bf16x8 af[4], bfr[4];
#pragma unroll
      for (int i = 0; i < 4; ++i)
        af[i] = ld_sw(&As[wr * 64 + i * 16 + ln15][0], c * 4 + g, rsw);
#pragma unroll
      for (int j = 0; j < 4; ++j)
        bfr[j] = ld_sw(&Bs[wc * 64 + j * 16 + ln15][0], c * 4 + g, rsw);
#pragma unroll
      for (int i = 0; i < 4; ++i)
#pragma unroll
        for (int j = 0; j < 4; ++j)
          acc[i][j] = __builtin_amdgcn_mfma_f32_16x16x32_bf16(
              af[i], bfr[j], acc[i][j], 0, 0, 0);
    }
  }

  __syncthreads();                       // all MFMA frag reads done
  unsigned short* scr = SH + wave * 4096;  // per-wave 64x64 scratch (8 KB)

  const int bx = blockIdx.x;             // segment id: q<8, k<16, v else
  if (bx < 16) {
    const bool isk = (bx >= 8);
#pragma unroll
    for (int i = 0; i < 4; ++i) {
#pragma unroll
      for (int r = 0; r < 4; ++r) {
        float u[4];
        float part = 0.f;
#pragma unroll
        for (int j = 0; j < 4; ++j) {
          u[j] = acc[i][j][r] + bias[n0 + wc * 64 + j * 16 + ln15];
          float sq = u[j] * u[j];
          if (j == 0 && ln15 == 0) sq = -sq;     // time component
          part += sq;
        }
#pragma unroll
        for (int off = 1; off < 16; off <<= 1)
          part += __shfl_xor(part, off, 64);
        const float nomin = sqrtf(fmaxf(part, 1e-8f));
        const float e = __expf(nomin);
        const float ei = __builtin_amdgcn_rcpf(e);
        const float tim = 0.5f * (e + ei);
        const float coef = 0.5f * (e - ei) * __builtin_amdgcn_rcpf(nomin);
        const int lrow = i * 16 + g * 4 + r;     // token-local 0..63
#pragma unroll
        for (int j = 0; j < 4; ++j) {
          float o = (j == 0 && ln15 == 0) ? tim : coef * u[j];
          if (isk && !(j == 0 && ln15 == 0)) o = -o;
          const int col = j * 16 + ln15;
          const int ch = ((col >> 3) + lrow) & 7;
          scr[lrow * 64 + ch * 8 + (col & 7)] = f2b(o);
        }
      }
    }
#pragma unroll
    for (int it = 0; it < 8; ++it) {
      const int row = (lane >> 3) + 8 * it;    // 0..63
      const int ch = lane & 7;
      const int ph = (ch + row) & 7;
      const bf16x8 v = *(const bf16x8*)&scr[row * 64 + ph * 8];
      *(bf16x8*)&qkvb[(size_t)(m0 + wr * 64 + row) * NQKV + n0 + wc * 64 + ch * 8] = v;
    }
  } else {
#pragma unroll
    for (int i = 0; i < 4; ++i) {
#pragma unroll
      for (int j = 0; j < 4; ++j) {
        const float bb_ = bias[n0 + wc * 64 + j * 16 + ln15];
        const int drow = j * 16 + ln15;          // 0..63
#pragma unroll
        for (int r = 0; r < 4; ++r) {
          const int col = i * 16 + g * 4 + r;    // t-local 0..63
          const int ch = ((col >> 3) + drow) & 7;
          scr[drow * 64 + ch * 8 + (col & 7)] = f2b(acc[i][j][r] + bb_);
        }
      }
    }
    const int hh = (bx - 16) * 2 + wc;
    const int mbase = m0 + wr * 64;
    const int bq = mbase >> 10;
    const int t0 = mbase & 1023;
#pragma unroll
    for (int it = 0; it < 8; ++it) {
      const int drow = (lane >> 3) + 8 * it;   // 0..63
      const int ch = lane & 7;
      const int ph = (ch + drow) & 7;
      const bf16x8 v = *(const bf16x8*)&scr[drow * 64 + ph * 8];
      *(bf16x8*)&vT[((size_t)(bq * HH + hh) * DD + drow) * TT + t0 + ch * 8] = v;
    }
  }
}

// ---------------------------------------------------------------------------
// Out GEMM (verified r15): 128x64 tiles, 2/CU, XOR chunk swizzle.
// ---------------------------------------------------------------------------
__global__ __launch_bounds__(256) void gemm_out(
    const unsigned short* __restrict__ A, const unsigned short* __restrict__ BT,
    const float* __restrict__ bias, float* __restrict__ C) {
  const int N = CC, K = CC;
  __shared__ unsigned short As[128][64];   // 16 KB
  __shared__ unsigned short Bs[64][64];    // 8 KB
  const int tid = threadIdx.x;
  const int lane = tid & 63;
  const int wave = tid >> 6;
  const int wm = wave * 32;
  const int m0 = blockIdx.y * 128;
  const int n0 = blockIdx.x * 64;
  const int ln15 = lane & 15;
  const int g = lane >> 4;
  const int rsw = ln15 & 7;

  const int srow = tid >> 3;           // 0..31
  const int schk = ((tid & 7) ^ (srow & 7)) * 8;
  const unsigned short* gA = A + (size_t)(m0 + srow) * K + schk;
  const unsigned short* gB = BT + (size_t)(n0 + srow) * K + schk;
  char* lA = (char*)As + wave * 1024;
  char* lB = (char*)Bs + wave * 1024;

  f32x4 acc[2][4] = {};

  for (int k0 = 0; k0 < K; k0 += 64) {
    __syncthreads();
#pragma unroll
    for (int i = 0; i < 4; ++i)
      gload16(gA + k0 + (size_t)(32 * i) * K, lA + i * 4096);
#pragma unroll
    for (int i = 0; i < 2; ++i)
      gload16(gB + k0 + (size_t)(32 * i) * K, lB + i * 4096);
    __syncthreads();

#pragma unroll
    for (int c = 0; c < 2; ++c) {
      bf16x8 af[2], bfr[4];
#pragma unroll
      for (int i = 0; i < 2; ++i)
        af[i] = ld_sw(&As[wm + i * 16 + ln15][0], c * 4 + g, rsw);
#pragma unroll
      for (int j = 0; j < 4; ++j)
        bfr[j] = ld_sw(&Bs[j * 16 + ln15][0], c * 4 + g, rsw);
#pragma unroll
      for (int i = 0; i < 2; ++i)
#pragma unroll
        for (int j = 0; j < 4; ++j)
          acc[i][j] = __builtin_amdgcn_mfma_f32_16x16x32_bf16(
              af[i], bfr[j], acc[i][j], 0, 0, 0);
    }
  }

#pragma unroll
  for (int i = 0; i < 2; ++i) {
#pragma unroll
    for (int r = 0; r < 4; ++r) {
      const int m = m0 + wm + i * 16 + g * 4 + r;
#pragma unroll
      for (int j = 0; j < 4; ++j) {
        const int n = n0 + j * 16 + ln15;
        C[(size_t)m * N + n] = acc[i][j][r] + bias[n];
      }
    }
  }
}

// ---------------------------------------------------------------------------
// MFMA flash, 128-row Q blocks (verified r17/r18) + r22: T5 setprio around
// the QK and PV MFMA clusters. Flash is latency-bound (r19 profile: MfmaUtil
// 3.9%, VALUBusy 14.7%, Occ 9.8%) with 2 independent blocks/CU whose waves
// drift between the per-128-col barriers — setprio lets MFMA-issuing waves
// preempt trans/VALU-busy waves (m191: +4-7% on attn with this shape).
// LDS: Ks[128][68] + Vs[64][136] + Ps[128][68] = 52.2 KB.
// ---------------------------------------------------------------------------
__global__ __launch_bounds__(512) void flash_mfma(
    const unsigned short* __restrict__ qkv, const unsigned short* __restrict__ vT,
    const float* __restrict__ spikes, unsigned short* __restrict__ y) {
  __shared__ unsigned short Ks[128][68];
  __shared__ unsigned short Vs[64][136];   // Vs[d][t-local 0..127]
  __shared__ unsigned short Ps[128][68];

  const int tid = threadIdx.x;
  const int lane = tid & 63;
  const int wave = tid >> 6;              // 0..7
  const int ln15 = lane & 15;
  const int g = lane >> 4;
  const int bh = blockIdx.y;
  const int itile = (bh < 32) ? ((int)gridDim.x - 1 - (int)blockIdx.x)
                              : (int)blockIdx.x;   // balanced pairing
  const int b = bh >> 4;
  const int h = bh & 15;
  const int i0 = itile * 128;
  const int band = wave * 16;
  const int htiles = itile + 1;           // 128-col iterations
  const unsigned short* base = qkv + (size_t)b * TT * NQKV;
  const unsigned short* vbase = vT + (size_t)bh * DD * TT;  // rows d, cols t
  const int qoff = h * DD;
  const int koff = CC + h * DD;

  // staging coords
  const int ksn = tid >> 2;            // K row 0..127
  const int kqc = (tid & 3) * 2;       // two 16-B chunks of the 128-B row
  const int vsn = tid >> 3;            // V d-row 0..63
  const int vqc = (tid & 7) * 2;       // two 16-B chunks of the 256-B row

  bf16x8 qf[2];
  {
    const unsigned short* qp = base + (size_t)(i0 + band + ln15) * NQKV + qoff;
    qf[0] = *(const bf16x8*)(qp + g * 8);
    qf[1] = *(const bf16x8*)(qp + 32 + g * 8);
  }

  f32x4 accy[4] = {};           // y[m=g*4+r][d=dt*16+ln15] (unnormalized)
  float lrow[4] = {0.f, 0.f, 0.f, 0.f};

  // prefetch iteration 0
  float4 kr0, kr1, vr0, vr1;
  {
    const unsigned short* kp = base + (size_t)ksn * NQKV + koff + kqc * 8;
    const unsigned short* vp = vbase + (size_t)vsn * TT + vqc * 8;
    kr0 = *(const float4*)(kp + 0);
    kr1 = *(const float4*)(kp + 8);
    vr0 = *(const float4*)(vp + 0);
    vr1 = *(const float4*)(vp + 8);
  }

  for (int ht = 0; ht < htiles; ++ht) {
    const int j0h = ht * 128;
    __syncthreads();                       // prior-iter Ks/Vs consumers done
    *(float4*)&Ks[ksn][kqc * 8 + 0] = kr0;
    *(float4*)&Ks[ksn][kqc * 8 + 8] = kr1;
    *(float4*)&Vs[vsn][vqc * 8 + 0] = vr0;
    *(float4*)&Vs[vsn][vqc * 8 + 8] = vr1;
    __syncthreads();

    // prefetch next iteration (overlaps with compute below)
    if (ht + 1 < htiles) {
      const int j1 = j0h + 128;
      const unsigned short* kp = base + (size_t)(j1 + ksn) * NQKV + koff + kqc * 8;
      const unsigned short* vp = vbase + (size_t)vsn * TT + j1 + vqc * 8;
      kr0 = *(const float4*)(kp + 0);
      kr1 = *(const float4*)(kp + 8);
      vr0 = *(const float4*)(vp + 0);
      vr1 = *(const float4*)(vp + 8);
    }

#pragma unroll
    for (int t2 = 0; t2 < 2; ++t2) {
      const int j0 = j0h + t2 * 64;
      if (j0 > i0 + band + 15) continue;   // fully masked for this band

      // S = Q . K^T  (K rows t2*64 .. +63)
      f32x4 sf[4];
      __builtin_amdgcn_s_setprio(1);
#pragma unroll
      for (int j = 0; j < 4; ++j) {
        const bf16x8 k0 = *(const bf16x8*)&Ks[t2 * 64 + j * 16 + ln15][g * 8];
        const bf16x8 k1 = *(const bf16x8*)&Ks[t2 * 64 + j * 16 + ln15][32 + g * 8];
        f32x4 z = {};
        z = __builtin_amdgcn_mfma_f32_16x16x32_bf16(qf[0], k0, z, 0, 0, 0);
        sf[j] = __builtin_amdgcn_mfma_f32_16x16x32_bf16(qf[1], k1, z, 0, 0, 0);
      }
      __builtin_amdgcn_s_setprio(0);

      // p = exp2(-(ln2/8) * (log2(z)+1)^2);  ln2/8 = 0.08664339757
      float p[4][4];
      if (j0 + 63 <= i0 + band) {
        // unmasked fast path (strictly below diagonal for this wave)
#pragma unroll
        for (int j = 0; j < 4; ++j)
#pragma unroll
          for (int r = 0; r < 4; ++r) {
            const float l = hw_log2(fmaxf(sf[j][r], 1.0f));
            const float s = l + 1.0f;
            p[r][j] = hw_exp2(-0.08664339757f * s * s);
          }
      } else {
#pragma unroll
        for (int j = 0; j < 4; ++j) {
          const int gj = j0 + j * 16 + ln15;
#pragma unroll
          for (int r = 0; r < 4; ++r) {
            const int gi = i0 + band + g * 4 + r;
            float e;
            if (gj > gi) {
              e = 0.f;
            } else {
              const float l = hw_log2(fmaxf(sf[j][r], 1.0f));
              const float s = l + 1.0f;
              e = hw_exp2(-0.08664339757f * s * s);
            }
            p[r][j] = e;
          }
        }
      }
#pragma unroll
      for (int r = 0; r < 4; ++r)
        lrow[r] += (p[r][0] + p[r][1]) + (p[r][2] + p[r][3]);

      // P -> LDS (bf16, A-layout); intra-wave producer/consumer, no barrier
#pragma unroll
      for (int r = 0; r < 4; ++r)
#pragma unroll
        for (int j = 0; j < 4; ++j)
          Ps[band + g * 4 + r][j * 16 + ln15] = f2b(p[r][j]);

      const bf16x8 pa0 = *(const bf16x8*)&Ps[band + ln15][g * 8];
      const bf16x8 pa1 = *(const bf16x8*)&Ps[band + ln15][32 + g * 8];
      __builtin_amdgcn_s_setprio(1);
#pragma unroll
      for (int dt = 0; dt < 4; ++dt) {
        const bf16x8 v0 = *(const bf16x8*)&Vs[dt * 16 + ln15][t2 * 64 + g * 8];
        const bf16x8 v1 = *(const bf16x8*)&Vs[dt * 16 + ln15][t2 * 64 + 32 + g * 8];
        accy[dt] = __builtin_amdgcn_mfma_f32_16x16x32_bf16(pa0, v0, accy[dt], 0, 0, 0);
        accy[dt] = __builtin_amdgcn_mfma_f32_16x16x32_bf16(pa1, v1, accy[dt], 0, 0, 0);
      }
      __builtin_amdgcn_s_setprio(0);
    }
  }

  // epilogue: reduce lrow across the 16 n-lanes, scale, store
#pragma unroll
  for (int r = 0; r < 4; ++r) {
#pragma unroll
    for (int off = 1; off < 16; off <<= 1)
      lrow[r] += __shfl_xor(lrow[r], off, 64);
  }
  const int grow = b * TT + i0 + band + g * 4;
#pragma unroll
  for (int r = 0; r < 4; ++r) {
    const float spk = spikes[grow + r];
    const float scale = spk / lrow[r];
#pragma unroll
    for (int dt = 0; dt < 4; ++dt)
      y[(size_t)(grow + r) * CC + h * DD + dt * 16 + ln15] =
          f2b(accy[dt][r] * scale);
  }
}

// ---------------------------------------------------------------------------
extern "C" void kernel_launch(void* const* d_in, const int* in_sizes, int n_in,
                              void* d_out, int out_size, void* d_ws, size_t ws_size,
                              hipStream_t stream) {
  const float* x     = (const float*)d_in[0];
  const float* W_qkv = (const float*)d_in[1];
  const float* b_qkv = (const float*)d_in[2];
  const float* W_out = (const float*)d_in[3];
  const float* b_out = (const float*)d_in[4];
  const float* w_sur = (const float*)d_in[5];
  const float* b_sur = (const float*)d_in[6];
  const float* thr   = (const float*)d_in[7];
  float* out = (float*)d_out;

  // ws layout (bytes, total ~58.8 MB):
  //   xb 8.39M | qkvb 25.17M | vT 8.39M | ybufb 8.39M | WqkvT 6.29M |
  //   WoutT 2.10M | spikes 16K
  char* w = (char*)d_ws;
  unsigned short* xb    = (unsigned short*)(w);
  unsigned short* qkvb  = (unsigned short*)(w + 8388608);
  unsigned short* vTb   = (unsigned short*)(w + 8388608 + 25165824);
  unsigned short* ybufb = (unsigned short*)(w + 8388608 + 25165824 + 8388608);
  unsigned short* WqkvT = (unsigned short*)(w + 8388608 + 25165824 + 2 * 8388608);
  unsigned short* WoutT = (unsigned short*)(w + 8388608 + 25165824 + 2 * 8388608 + 6291456);
  float* spikes = (float*)(w + 8388608 + 25165824 + 2 * 8388608 + 6291456 + 2097152);

  prep<<<5120, 256, 0, stream>>>(x, w_sur, b_sur, thr, W_qkv, W_out,
                                 spikes, xb, WqkvT, WoutT);

  gemm_qkv<<<dim3(NQKV / 128, MROWS / 128), 256, 0, stream>>>(
      xb, WqkvT, b_qkv, qkvb, vTb);

  flash_mfma<<<dim3(TT / 128, BB * HH), 512, 0, stream>>>(qkvb, vTb, spikes, ybufb);

  gemm_out<<<dim3(CC / 64, MROWS / 128), 256, 0, stream>>>(
      ybufb, WoutT, b_out, out);
}